// Round 16
// baseline (1144.603 us; speedup 1.0000x reference)
//
#include <hip/hip_runtime.h>
#include <stdint.h>

// ---------------------------------------------------------------------------
// ConditionalDecoder: emb-gather -> LSTM x2 -> FiLM -> vocab GEMM
// B=16, T=256, V=32000, E=H=Z=256, 4H=1024
// Round 16: un-fuse the vocab GEMM (r12/r14/r15 all showed concurrent vocab
//   traffic stretches the latency-critical pipeline ~2x via LLC thrash).
//   - k_fused: 64 blocks (X0proj || L0 || X1proj || L1), r11-proven 504us.
//   - k_vocab: trailing dispatch, r15-proven tile math + full-line 512B
//     wave-contiguous stores (no write-allocate RMW), m-tile-fastest order.
//   - prep: 2 grid-stride launches.
// ---------------------------------------------------------------------------

#define B_  16
#define T_  256
#define H_  256
#define V_  32000
#define G4  1024

#define LTPB 512   // 8 waves
#define FSTR 32    // flag stride in ints (one 128B line per flag)

typedef unsigned short u16;
typedef unsigned long long u64;
typedef __attribute__((ext_vector_type(8))) short  short8;
typedef __attribute__((ext_vector_type(4))) short  short4v;
typedef __attribute__((ext_vector_type(4))) float  f32x4;
typedef __attribute__((ext_vector_type(2))) float  f32x2;

static __device__ __forceinline__ float bf2f(u16 u) {
  uint32_t i = ((uint32_t)u) << 16;
  return __builtin_bit_cast(float, i);
}
static __device__ __forceinline__ u16 f2bf(float f) {
  uint32_t i = __builtin_bit_cast(uint32_t, f);
  uint32_t lsb = (i >> 16) & 1u;
  i += 0x7fffu + lsb;
  return (u16)(i >> 16);
}
static __device__ __forceinline__ float sigf(float x) {
  return 1.0f / (1.0f + __expf(-x));
}
static __device__ __forceinline__ float tanhfast(float x) {
  return 1.0f - 2.0f / (1.0f + __expf(2.0f * x));
}

// OCP e4m3fn encode (bias 7, max 448, RNE). Same encoder for W-pack and h.
static __device__ __forceinline__ uint32_t f32_to_e4m3(float f) {
  uint32_t u = __builtin_bit_cast(uint32_t, f);
  uint32_t s = (u >> 24) & 0x80u;
  uint32_t mag = u & 0x7fffffffu;
  if (mag >= 0x43E00000u) return s | 0x7Eu;
  if (mag < 0x3C800000u) {
    float af = __builtin_bit_cast(float, mag);
    int q = (int)rintf(af * 512.0f);
    if (q >= 8) return s | 0x08u;
    return s | (uint32_t)q;
  }
  uint32_t lsb = (mag >> 20) & 1u;
  mag += 0x7ffffu + lsb;
  int e = (int)(mag >> 23) - 120;
  uint32_t m3 = (mag >> 20) & 7u;
  if (e >= 16) return s | 0x7Eu;
  return s | ((uint32_t)e << 3) | m3;
}

// ------------------------------ prep kernels -------------------------------

// All bf16 converts + embedding gather, one grid-stride kernel.
__global__ void k_prepA(const float* __restrict__ Wih0, u16* __restrict__ Wih0b,
                        const float* __restrict__ Wih1, u16* __restrict__ Wih1b,
                        const float* __restrict__ Wout, u16* __restrict__ Woutb,
                        const int* __restrict__ seq, const float* __restrict__ emb,
                        u16* __restrict__ xb) {
  const int N1 = G4 * H_;                    // 262144
  const int N2 = N1 + G4 * H_;               // 524288
  const int N3 = N2 + V_ * H_;               // 8716288
  const int N4 = N3 + B_ * T_ * (H_ / 4);    // 8978432
  int stride = gridDim.x * blockDim.x;
  for (int i = blockIdx.x * blockDim.x + threadIdx.x; i < N4; i += stride) {
    if (i < N1) {
      Wih0b[i] = f2bf(Wih0[i]);
    } else if (i < N2) {
      int j = i - N1;
      Wih1b[j] = f2bf(Wih1[j]);
    } else if (i < N3) {
      int j = i - N2;
      Woutb[j] = f2bf(Wout[j]);
    } else {
      int j = i - N3;
      int e4 = j & 63, bt = j >> 6;
      int t = bt & 255, b = bt >> 8;
      int row = seq[b * 257 + t];
      short4v p;
      if (row == 0) {
        p[0] = 0; p[1] = 0; p[2] = 0; p[3] = 0;
      } else {
        f32x4 v = *(const f32x4*)(emb + (size_t)row * 256 + e4 * 4);
        p[0] = (short)f2bf(v[0]); p[1] = (short)f2bf(v[1]);
        p[2] = (short)f2bf(v[2]); p[3] = (short)f2bf(v[3]);
      }
      *(short4v*)(xb + (size_t)bt * 256 + e4 * 4) = p;
    }
  }
}

static __device__ __forceinline__ void packWg_body(
    const float* __restrict__ Whh, u16* __restrict__ pk, int i) {
  int lane = i & 63;
  int fb = (i >> 6) & 15;
  int w  = i >> 10;
  int cb = fb >> 3, ks = fb & 7;
  int row = 512 + w * 32 + cb * 16 + (lane & 15);
  int kb  = ks * 32 + (lane >> 4) * 8;
  const float* src = Whh + (size_t)row * 256 + kb;
  short8 v;
  #pragma unroll
  for (int j = 0; j < 8; j++) v[j] = (short)f2bf(src[j]);
  *(short8*)(pk + (size_t)i * 8) = v;
}

static __device__ __forceinline__ void packW8_body(
    const float* __restrict__ Whh, u64* __restrict__ pk, int i) {
  int lane = i & 63;
  int fo = (i >> 6) % 48;
  int w  = (i >> 6) / 48;
  int g8 = fo >> 4, cb = (fo >> 3) & 1, ks = fo & 7;
  int base = (g8 == 0) ? 0 : (g8 == 1 ? 256 : 768);
  int row = base + w * 32 + cb * 16 + (lane & 15);
  int kb  = ks * 32 + (lane >> 4) * 8;
  const float* src = Whh + (size_t)row * 256 + kb;
  u64 p = 0;
  #pragma unroll
  for (int j = 0; j < 8; j++)
    p |= ((u64)f32_to_e4m3(src[j])) << (8 * j);
  pk[i] = p;
}

// W_hh packs + FiLM + bias sums + flag zeroing (304 blocks x 256).
__global__ void k_prepB(const float* __restrict__ Whh0, u16* __restrict__ WpG0,
                        u64* __restrict__ Wp80,
                        const float* __restrict__ Whh1, u16* __restrict__ WpG1,
                        u64* __restrict__ Wp81,
                        const float* __restrict__ z,
                        const float* __restrict__ Wg, const float* __restrict__ bg,
                        const float* __restrict__ Wb, const float* __restrict__ bb,
                        float* __restrict__ gamma, float* __restrict__ beta,
                        const float* __restrict__ bih0, const float* __restrict__ bhh0,
                        float* __restrict__ b01,
                        const float* __restrict__ bih1, const float* __restrict__ bhh1,
                        float* __restrict__ b11,
                        int* __restrict__ flags) {
  int i = blockIdx.x * blockDim.x + threadIdx.x;
  if (i < 8192) {
    packWg_body(Whh0, WpG0, i);
  } else if (i < 16384) {
    packWg_body(Whh1, WpG1, i - 8192);
  } else if (i < 40960) {
    packW8_body(Whh0, Wp80, i - 16384);
  } else if (i < 65536) {
    packW8_body(Whh1, Wp81, i - 40960);
  } else if (i < 73728) {
    int o = i - 65536;            // 8192: gamma|beta
    int which = o >> 12;
    int p = o & 4095;
    int b = p >> 8, h = p & 255;
    const float* W  = which ? Wb : Wg;
    const float* bi = which ? bb : bg;
    float acc = bi[h];
    const float* zr = z + b * 256;
    const float* wr = W + h * 256;
    #pragma unroll 8
    for (int k = 0; k < 256; k++) acc += zr[k] * wr[k];
    (which ? beta : gamma)[p] = acc;
  } else if (i < 74752) {
    int j = i - 73728;
    b01[j] = bih0[j] + bhh0[j];
  } else if (i < 75776) {
    int j = i - 74752;
    b11[j] = bih1[j] + bhh1[j];
  } else if (i < 77824) {
    flags[i - 75776] = 0;          // flagX..flagC, 2048 ints contiguous
  }
}

// ----------------------------- fused roles ---------------------------------

static __device__ __forceinline__ void lstm_role(
    const float* __restrict__ Xpre, const u16* __restrict__ WpkG,
    const u64* __restrict__ Wpk8, u16* __restrict__ outb,
    const float* __restrict__ gamma, const float* __restrict__ beta,
    int mode, int s, int* flagOut, const int* flagIn,
    u16 (*hbuf)[256], u64 (*h8buf)[32]) {
  const int tid  = threadIdx.x;
  const int lane = tid & 63;
  const int w    = tid >> 6;
  const int l15  = lane & 15;
  const int lhi  = lane >> 4;

  short8 wgm[16];
  {
    const u16* bp = WpkG + ((size_t)(w * 16) * 64 + lane) * 8;
    #pragma unroll
    for (int f = 0; f < 16; ++f)
      wgm[f] = *(const short8*)(bp + (size_t)f * 512);
  }
  u64 w8r[48];
  {
    const u64* p8 = Wpk8 + (size_t)(w * 48) * 64 + lane;
    #pragma unroll
    for (int f = 0; f < 48; ++f)
      w8r[f] = p8[(size_t)f * 64];
  }

  const int col0 = w * 32 + l15;
  const int col1 = col0 + 16;
  float cs0 = 0.f, cs1 = 0.f;
  float gm0 = 1.f, gm1 = 1.f, bt0 = 0.f, bt1 = 0.f;
  if (mode) {
    gm0 = gamma[s * 256 + col0]; bt0 = beta[s * 256 + col0];
    gm1 = gamma[s * 256 + col1]; bt1 = beta[s * 256 + col1];
  }

  if (flagIn) {
    if (tid == 0) {
      while (__hip_atomic_load(flagIn, __ATOMIC_RELAXED,
                               __HIP_MEMORY_SCOPE_AGENT) < 1) { }
    }
    __syncthreads();
    __builtin_amdgcn_fence(__ATOMIC_ACQUIRE, "agent");
  }

  const float* xptr = Xpre + (size_t)s * T_ * 1024 + (size_t)(w * 16 + l15) * 8;

  // ---- t = 0 ----
  f32x4 xa = *(const f32x4*)(xptr);
  f32x4 xg = *(const f32x4*)(xptr + 4);
  {
    float cn0 = sigf(xa[2]) * cs0 + sigf(xa[0]) * tanhfast(xg[0]);
    float hn0 = sigf(xg[2]) * tanhfast(cn0);
    cs0 = cn0;
    float cn1 = sigf(xa[3]) * cs1 + sigf(xa[1]) * tanhfast(xg[1]);
    float hn1 = sigf(xg[3]) * tanhfast(cn1);
    cs1 = cn1;
    u16 h0 = f2bf(hn0), h1 = f2bf(hn1);
    if (lhi == 0) {
      hbuf[0][col0] = h0;
      hbuf[0][col1] = h1;
      ((uint8_t*)h8buf[0])[col0] = (uint8_t)f32_to_e4m3(hn0);
      ((uint8_t*)h8buf[0])[col1] = (uint8_t)f32_to_e4m3(hn1);
      outb[(size_t)(s * T_) * 256 + col0] = mode ? f2bf(gm0 * hn0 + bt0) : h0;
      outb[(size_t)(s * T_) * 256 + col1] = mode ? f2bf(gm1 * hn1 + bt1) : h1;
    }
  }
  asm volatile("s_waitcnt lgkmcnt(0)" ::: "memory");
  __builtin_amdgcn_sched_barrier(0);
  __builtin_amdgcn_s_barrier();
  __builtin_amdgcn_sched_barrier(0);

  xa = *(const f32x4*)(xptr + 1024);
  xg = *(const f32x4*)(xptr + 1024 + 4);

  for (int t = 1; t < T_; ++t) {
    if (flagIn && (t & 15) == 15 && (t + 1) < T_) {
      const int need = ((t + 1) >> 4) + 1;
      if (tid == 0) {
        while (__hip_atomic_load(flagIn, __ATOMIC_RELAXED,
                                 __HIP_MEMORY_SCOPE_AGENT) < need) { }
      }
      __syncthreads();
      __builtin_amdgcn_fence(__ATOMIC_ACQUIRE, "agent");
    }

    const float* xn = xptr + (size_t)((t + 1 < T_) ? t + 1 : t) * 1024;
    f32x4 na = *(const f32x4*)(xn);
    f32x4 ng = *(const f32x4*)(xn + 4);

    const u16* hrd  = hbuf[(t + 1) & 1];
    const u64* h8rd = h8buf[(t + 1) & 1];

    f32x4 aI[2], aF[2], aG[2], aO[2];
    #pragma unroll
    for (int i = 0; i < 2; ++i) {
      aI[i] = (f32x4){0.f, 0.f, 0.f, 0.f};
      aF[i] = (f32x4){0.f, 0.f, 0.f, 0.f};
      aG[i] = (f32x4){0.f, 0.f, 0.f, 0.f};
      aO[i] = (f32x4){0.f, 0.f, 0.f, 0.f};
    }
    #pragma unroll
    for (int ks = 0; ks < 8; ++ks) {
      short8 a  = *(const short8*)&hrd[ks * 32 + lhi * 8];
      u64    a8 = h8rd[ks * 4 + lhi];
      aG[0] = __builtin_amdgcn_mfma_f32_16x16x32_bf16(a, wgm[ks],     aG[0], 0, 0, 0);
      aG[1] = __builtin_amdgcn_mfma_f32_16x16x32_bf16(a, wgm[8 + ks], aG[1], 0, 0, 0);
      aI[0] = __builtin_amdgcn_mfma_f32_16x16x32_fp8_fp8((long)a8, (long)w8r[ks],      aI[0], 0, 0, 0);
      aI[1] = __builtin_amdgcn_mfma_f32_16x16x32_fp8_fp8((long)a8, (long)w8r[8 + ks],  aI[1], 0, 0, 0);
      aF[0] = __builtin_amdgcn_mfma_f32_16x16x32_fp8_fp8((long)a8, (long)w8r[16 + ks], aF[0], 0, 0, 0);
      aF[1] = __builtin_amdgcn_mfma_f32_16x16x32_fp8_fp8((long)a8, (long)w8r[24 + ks], aF[1], 0, 0, 0);
      aO[0] = __builtin_amdgcn_mfma_f32_16x16x32_fp8_fp8((long)a8, (long)w8r[32 + ks], aO[0], 0, 0, 0);
      aO[1] = __builtin_amdgcn_mfma_f32_16x16x32_fp8_fp8((long)a8, (long)w8r[40 + ks], aO[1], 0, 0, 0);
    }

    float iv0 = aI[0][0] + xa[0], iv1 = aI[1][0] + xa[1];
    float fv0 = aF[0][0] + xa[2], fv1 = aF[1][0] + xa[3];
    float gv0 = aG[0][0] + xg[0], gv1 = aG[1][0] + xg[1];
    float ov0 = aO[0][0] + xg[2], ov1 = aO[1][0] + xg[3];

    float cn0 = sigf(fv0) * cs0 + sigf(iv0) * tanhfast(gv0);
    float hn0 = sigf(ov0) * tanhfast(cn0);
    cs0 = cn0;
    float cn1 = sigf(fv1) * cs1 + sigf(iv1) * tanhfast(gv1);
    float hn1 = sigf(ov1) * tanhfast(cn1);
    cs1 = cn1;

    u16 h0 = f2bf(hn0), h1 = f2bf(hn1);
    if (lhi == 0) {
      hbuf[t & 1][col0] = h0;
      hbuf[t & 1][col1] = h1;
      ((uint8_t*)h8buf[t & 1])[col0] = (uint8_t)f32_to_e4m3(hn0);
      ((uint8_t*)h8buf[t & 1])[col1] = (uint8_t)f32_to_e4m3(hn1);
      outb[((size_t)(s * T_ + t)) * 256 + col0] = mode ? f2bf(gm0 * hn0 + bt0) : h0;
      outb[((size_t)(s * T_ + t)) * 256 + col1] = mode ? f2bf(gm1 * hn1 + bt1) : h1;
    }

    if (flagOut && (t & 15) == 15) {
      __syncthreads();
      if (tid == 0) {
        __builtin_amdgcn_fence(__ATOMIC_RELEASE, "agent");
        __hip_atomic_store(flagOut, t + 1, __ATOMIC_RELAXED,
                           __HIP_MEMORY_SCOPE_AGENT);
      }
    } else {
      asm volatile("s_waitcnt lgkmcnt(0)" ::: "memory");
      __builtin_amdgcn_sched_barrier(0);
      __builtin_amdgcn_s_barrier();
      __builtin_amdgcn_sched_barrier(0);
    }

    xa = na;
    xg = ng;
  }
}

// gate-projection worker: dst(s, t0..t0+15, :) = src rows @ W^T + bias (permuted)
static __device__ __forceinline__ void proj_role(
    const u16* __restrict__ src, const u16* __restrict__ Wb_,
    const float* __restrict__ bias, float* __restrict__ dst,
    int s, const int* flagIn, int* flagOut) {
  const int tid  = threadIdx.x;
  const int lane = tid & 63;
  const int w    = tid >> 6;
  const int l15  = lane & 15;
  const int lhi  = lane >> 4;

  for (int tc = 0; tc < 16; ++tc) {
    if (flagIn) {
      const int need = (tc + 1) * 16;
      if (tid == 0) {
        while (__hip_atomic_load(flagIn, __ATOMIC_RELAXED,
                                 __HIP_MEMORY_SCOPE_AGENT) < need) { }
      }
      __syncthreads();
      __builtin_amdgcn_fence(__ATOMIC_ACQUIRE, "agent");
    }

    const int t0 = tc * 16;
    short8 afr[8];
    #pragma unroll
    for (int ks = 0; ks < 8; ++ks)
      afr[ks] = *(const short8*)(src + ((size_t)(s * T_ + t0 + l15)) * 256 + ks * 32 + lhi * 8);

    #pragma unroll
    for (int nt = 0; nt < 8; ++nt) {
      const int colb = w * 128 + nt * 16 + l15;
      f32x4 acc = (f32x4){0.f, 0.f, 0.f, 0.f};
      const u16* bp = Wb_ + (size_t)colb * 256 + lhi * 8;
      #pragma unroll
      for (int ks = 0; ks < 8; ++ks) {
        short8 bf = *(const short8*)(bp + ks * 32);
        acc = __builtin_amdgcn_mfma_f32_16x16x32_bf16(afr[ks], bf, acc, 0, 0, 0);
      }
      const int g = colb >> 8, r = colb & 255;
      const int ocol = (r >> 5) * 128 + (r & 15) * 8 + g * 2 + ((r >> 4) & 1);
      const float bv = bias[colb];
      #pragma unroll
      for (int i = 0; i < 4; ++i) {
        int trow = t0 + lhi * 4 + i;
        dst[((size_t)(s * T_ + trow)) * 1024 + ocol] = acc[i] + bv;
      }
    }

    __syncthreads();
    if (tid == 0) {
      __builtin_amdgcn_fence(__ATOMIC_RELEASE, "agent");
      __hip_atomic_store(flagOut, tc + 1, __ATOMIC_RELAXED,
                         __HIP_MEMORY_SCOPE_AGENT);
    }
  }
}

__global__ __launch_bounds__(LTPB, 2) void k_fused(
    const u16* __restrict__ xb, float* __restrict__ X0, float* __restrict__ X1,
    const u16* __restrict__ WpG0, const u64* __restrict__ Wp80,
    const u16* __restrict__ WpG1, const u64* __restrict__ Wp81,
    const u16* __restrict__ Wih0b, const float* __restrict__ b01,
    const u16* __restrict__ Wih1b, const float* __restrict__ b11,
    u16* __restrict__ h1b, u16* __restrict__ filmb,
    const float* __restrict__ gamma, const float* __restrict__ beta,
    int* __restrict__ flagX, int* __restrict__ flagA,
    int* __restrict__ flagB, int* __restrict__ flagC) {
  __shared__ __align__(16) char smem[1536];

  const int bid = blockIdx.x;
  if (bid < 16) {
    proj_role(xb, Wih0b, b01, X0, bid, nullptr, &flagX[bid * FSTR]);
  } else if (bid < 32) {
    const int s = bid - 16;
    lstm_role(X0, WpG0, Wp80, h1b, gamma, beta, 0, s,
              &flagA[s * FSTR], &flagX[s * FSTR],
              (u16(*)[256])smem, (u64(*)[32])(smem + 1024));
  } else if (bid < 48) {
    const int s = bid - 32;
    proj_role(h1b, Wih1b, b11, X1, s, &flagA[s * FSTR], &flagB[s * FSTR]);
  } else {
    const int s = bid - 48;
    lstm_role(X1, WpG1, Wp81, filmb, gamma, beta, 1, s,
              &flagC[s * FSTR], &flagB[s * FSTR],
              (u16(*)[256])smem, (u64(*)[32])(smem + 1024));
  }
}

// ------------------------- trailing vocab GEMM -----------------------------
// Tiles (M=64, N=128), m-tile-fastest order (consecutive blocks reuse the
// same Wo columns). A-frags direct from L2/LLC; epilogue staged in LDS ->
// per-instruction wave-contiguous 512B (4 full lines) stores: no RMW fetch.
__global__ __launch_bounds__(LTPB, 2) void k_vocab(
    const u16* __restrict__ filmb, const u16* __restrict__ Wo,
    const float* __restrict__ bout, float* __restrict__ out) {
  __shared__ float sC[64 * 132];
  const int tid  = threadIdx.x;
  const int lane = tid & 63;
  const int w    = tid >> 6;
  const int l15  = lane & 15;
  const int lhi  = lane >> 4;

  for (int j = blockIdx.x; j < 16000; j += gridDim.x) {
    const int mt = j & 63;          // m-tile fastest
    const int nt = j >> 6;          // 0..249
    const int m0 = mt * 64;
    const int n0 = nt * 128;
    const int colb = n0 + w * 16 + l15;

    short8 bfr[8];
    #pragma unroll
    for (int ks = 0; ks < 8; ++ks)
      bfr[ks] = *(const short8*)(Wo + (size_t)colb * 256 + ks * 32 + lhi * 8);

    f32x4 acc[4];
    #pragma unroll
    for (int mi = 0; mi < 4; ++mi) acc[mi] = (f32x4){0.f, 0.f, 0.f, 0.f};
    #pragma unroll
    for (int mi = 0; mi < 4; ++mi) {
      #pragma unroll
      for (int ks = 0; ks < 8; ++ks) {
        short8 a = *(const short8*)(filmb +
            ((size_t)(m0 + mi * 16 + l15)) * 256 + ks * 32 + lhi * 8);
        acc[mi] = __builtin_amdgcn_mfma_f32_16x16x32_bf16(a, bfr[ks], acc[mi], 0, 0, 0);
      }
    }

    const float bv = bout[colb];
    #pragma unroll
    for (int mi = 0; mi < 4; ++mi)
      #pragma unroll
      for (int i = 0; i < 4; ++i)
        sC[(mi * 16 + lhi * 4 + i) * 132 + w * 16 + l15] = acc[mi][i] + bv;
    __syncthreads();

    // wave w owns rows [w*8, w*8+8); lane l writes 8B at col l*2 ->
    // one instruction = 512B contiguous = 4 full cache lines.
    {
      const int rbase = w * 8;
      #pragma unroll
      for (int r = 0; r < 8; ++r) {
        const int row = rbase + r;
        f32x2 v;
        v[0] = sC[row * 132 + lane * 2];
        v[1] = sC[row * 132 + lane * 2 + 1];
        *(f32x2*)(out + (size_t)(m0 + row) * V_ + n0 + lane * 2) = v;
      }
    }
    __syncthreads();   // WAR: sC reused next tile
  }
}

// ------------------------------ launcher -----------------------------------

extern "C" void kernel_launch(void* const* d_in, const int* in_sizes, int n_in,
                              void* d_out, int out_size, void* d_ws, size_t ws_size,
                              hipStream_t stream) {
  const float* z    = (const float*)d_in[0];
  const int*   seq  = (const int*)  d_in[1];
  const float* emb  = (const float*)d_in[2];
  const float* Wg   = (const float*)d_in[3];
  const float* bg   = (const float*)d_in[4];
  const float* Wb   = (const float*)d_in[5];
  const float* bb   = (const float*)d_in[6];
  const float* Wih0 = (const float*)d_in[7];
  const float* Whh0 = (const float*)d_in[8];
  const float* bih0 = (const float*)d_in[9];
  const float* bhh0 = (const float*)d_in[10];
  const float* Wih1 = (const float*)d_in[11];
  const float* Whh1 = (const float*)d_in[12];
  const float* bih1 = (const float*)d_in[13];
  const float* bhh1 = (const float*)d_in[14];
  const float* Wout = (const float*)d_in[15];
  const float* bout = (const float*)d_in[16];

  char* ws = (char*)d_ws;
  size_t off = 0;
  auto take = [&](size_t bytes) -> char* {
    char* p = ws + off;
    off = (off + bytes + 255) & ~(size_t)255;
    return p;
  };
  float* gamma  = (float*)take(B_ * H_ * 4);
  float* beta   = (float*)take(B_ * H_ * 4);
  float* b01    = (float*)take(G4 * 4);
  float* b11    = (float*)take(G4 * 4);
  u16*   Wih0b  = (u16*)  take((size_t)G4 * H_ * 2);
  u16*   Wih1b  = (u16*)  take((size_t)G4 * H_ * 2);
  u16*   WpG0   = (u16*)  take((size_t)8 * 16 * 64 * 8 * 2);
  u64*   Wp80   = (u64*)  take((size_t)8 * 48 * 64 * 8);
  u16*   WpG1   = (u16*)  take((size_t)8 * 16 * 64 * 8 * 2);
  u64*   Wp81   = (u64*)  take((size_t)8 * 48 * 64 * 8);
  u16*   Woutb  = (u16*)  take((size_t)V_ * H_ * 2);
  u16*   xb     = (u16*)  take((size_t)B_ * T_ * H_ * 2);
  float* X0     = (float*)take((size_t)B_ * T_ * G4 * 4);
  float* X1     = (float*)take((size_t)B_ * T_ * G4 * 4);
  u16*   h1b    = (u16*)  take((size_t)B_ * T_ * H_ * 2);
  u16*   filmb  = (u16*)  take((size_t)B_ * T_ * H_ * 2);
  int*   flagX  = (int*)  take(B_ * FSTR * 4);
  int*   flagA  = (int*)  take(B_ * FSTR * 4);
  int*   flagB  = (int*)  take(B_ * FSTR * 4);
  int*   flagC  = (int*)  take(B_ * FSTR * 4);
  (void)ws_size; (void)in_sizes; (void)n_in; (void)out_size;

  // prep: 2 launches
  k_prepA<<<4096, 256, 0, stream>>>(Wih0, Wih0b, Wih1, Wih1b, Wout, Woutb,
                                    seq, emb, xb);
  k_prepB<<<304, 256, 0, stream>>>(Whh0, WpG0, Wp80, Whh1, WpG1, Wp81,
                                   z, Wg, bg, Wb, bb, gamma, beta,
                                   bih0, bhh0, b01, bih1, bhh1, b11, flagX);

  // fused pipeline: X0proj || L0 || X1proj || L1  (64 blocks)
  k_fused<<<64, LTPB, 0, stream>>>(
      xb, X0, X1, WpG0, Wp80, WpG1, Wp81, Wih0b, b01, Wih1b, b11,
      h1b, filmb, gamma, beta, flagX, flagA, flagB, flagC);

  // trailing vocab GEMM (full-line epilogue)
  k_vocab<<<1024, LTPB, 0, stream>>>(filmb, Woutb, bout, (float*)d_out);
}

// Round 17
// 958.506 us; speedup vs baseline: 1.1942x; 1.1942x over previous
//
#include <hip/hip_runtime.h>
#include <stdint.h>

// ---------------------------------------------------------------------------
// ConditionalDecoder: emb-gather -> LSTM x2 -> FiLM -> vocab GEMM
// B=16, T=256, V=32000, E=H=Z=256, 4H=1024
// Round 17: r16 with both measured regressions fixed.
//   - k_vocab: LDS-staged A tile (32KB, stride 264 -> 2-way-free b128 reads)
//     kills the 8x-redundant L2/LLC A-traffic that made r16's vocab 585us.
//     Full-line 512B epilogue kept (WRITE=512MB exact, no RMW).
//   - k_fused: L0 gates ONCE on flagX>=16 (r16's per-chunk acquire fences
//     on L0 cost ~95us; r11's fence-free L0 restored). X1proj/L1 unchanged.
// ---------------------------------------------------------------------------

#define B_  16
#define T_  256
#define H_  256
#define V_  32000
#define G4  1024

#define LTPB 512   // 8 waves
#define FSTR 32    // flag stride in ints (one 128B line per flag)

typedef unsigned short u16;
typedef unsigned long long u64;
typedef __attribute__((ext_vector_type(8))) short  short8;
typedef __attribute__((ext_vector_type(4))) short  short4v;
typedef __attribute__((ext_vector_type(4))) float  f32x4;
typedef __attribute__((ext_vector_type(2))) float  f32x2;

static __device__ __forceinline__ float bf2f(u16 u) {
  uint32_t i = ((uint32_t)u) << 16;
  return __builtin_bit_cast(float, i);
}
static __device__ __forceinline__ u16 f2bf(float f) {
  uint32_t i = __builtin_bit_cast(uint32_t, f);
  uint32_t lsb = (i >> 16) & 1u;
  i += 0x7fffu + lsb;
  return (u16)(i >> 16);
}
static __device__ __forceinline__ float sigf(float x) {
  return 1.0f / (1.0f + __expf(-x));
}
static __device__ __forceinline__ float tanhfast(float x) {
  return 1.0f - 2.0f / (1.0f + __expf(2.0f * x));
}

// OCP e4m3fn encode (bias 7, max 448, RNE). Same encoder for W-pack and h.
static __device__ __forceinline__ uint32_t f32_to_e4m3(float f) {
  uint32_t u = __builtin_bit_cast(uint32_t, f);
  uint32_t s = (u >> 24) & 0x80u;
  uint32_t mag = u & 0x7fffffffu;
  if (mag >= 0x43E00000u) return s | 0x7Eu;
  if (mag < 0x3C800000u) {
    float af = __builtin_bit_cast(float, mag);
    int q = (int)rintf(af * 512.0f);
    if (q >= 8) return s | 0x08u;
    return s | (uint32_t)q;
  }
  uint32_t lsb = (mag >> 20) & 1u;
  mag += 0x7ffffu + lsb;
  int e = (int)(mag >> 23) - 120;
  uint32_t m3 = (mag >> 20) & 7u;
  if (e >= 16) return s | 0x7Eu;
  return s | ((uint32_t)e << 3) | m3;
}

// ------------------------------ prep kernels -------------------------------

// All bf16 converts + embedding gather, one grid-stride kernel.
__global__ void k_prepA(const float* __restrict__ Wih0, u16* __restrict__ Wih0b,
                        const float* __restrict__ Wih1, u16* __restrict__ Wih1b,
                        const float* __restrict__ Wout, u16* __restrict__ Woutb,
                        const int* __restrict__ seq, const float* __restrict__ emb,
                        u16* __restrict__ xb) {
  const int N1 = G4 * H_;                    // 262144
  const int N2 = N1 + G4 * H_;               // 524288
  const int N3 = N2 + V_ * H_;               // 8716288
  const int N4 = N3 + B_ * T_ * (H_ / 4);    // 8978432
  int stride = gridDim.x * blockDim.x;
  for (int i = blockIdx.x * blockDim.x + threadIdx.x; i < N4; i += stride) {
    if (i < N1) {
      Wih0b[i] = f2bf(Wih0[i]);
    } else if (i < N2) {
      int j = i - N1;
      Wih1b[j] = f2bf(Wih1[j]);
    } else if (i < N3) {
      int j = i - N2;
      Woutb[j] = f2bf(Wout[j]);
    } else {
      int j = i - N3;
      int e4 = j & 63, bt = j >> 6;
      int t = bt & 255, b = bt >> 8;
      int row = seq[b * 257 + t];
      short4v p;
      if (row == 0) {
        p[0] = 0; p[1] = 0; p[2] = 0; p[3] = 0;
      } else {
        f32x4 v = *(const f32x4*)(emb + (size_t)row * 256 + e4 * 4);
        p[0] = (short)f2bf(v[0]); p[1] = (short)f2bf(v[1]);
        p[2] = (short)f2bf(v[2]); p[3] = (short)f2bf(v[3]);
      }
      *(short4v*)(xb + (size_t)bt * 256 + e4 * 4) = p;
    }
  }
}

static __device__ __forceinline__ void packWg_body(
    const float* __restrict__ Whh, u16* __restrict__ pk, int i) {
  int lane = i & 63;
  int fb = (i >> 6) & 15;
  int w  = i >> 10;
  int cb = fb >> 3, ks = fb & 7;
  int row = 512 + w * 32 + cb * 16 + (lane & 15);
  int kb  = ks * 32 + (lane >> 4) * 8;
  const float* src = Whh + (size_t)row * 256 + kb;
  short8 v;
  #pragma unroll
  for (int j = 0; j < 8; j++) v[j] = (short)f2bf(src[j]);
  *(short8*)(pk + (size_t)i * 8) = v;
}

static __device__ __forceinline__ void packW8_body(
    const float* __restrict__ Whh, u64* __restrict__ pk, int i) {
  int lane = i & 63;
  int fo = (i >> 6) % 48;
  int w  = (i >> 6) / 48;
  int g8 = fo >> 4, cb = (fo >> 3) & 1, ks = fo & 7;
  int base = (g8 == 0) ? 0 : (g8 == 1 ? 256 : 768);
  int row = base + w * 32 + cb * 16 + (lane & 15);
  int kb  = ks * 32 + (lane >> 4) * 8;
  const float* src = Whh + (size_t)row * 256 + kb;
  u64 p = 0;
  #pragma unroll
  for (int j = 0; j < 8; j++)
    p |= ((u64)f32_to_e4m3(src[j])) << (8 * j);
  pk[i] = p;
}

// W_hh packs + FiLM + bias sums + flag zeroing (304 blocks x 256).
__global__ void k_prepB(const float* __restrict__ Whh0, u16* __restrict__ WpG0,
                        u64* __restrict__ Wp80,
                        const float* __restrict__ Whh1, u16* __restrict__ WpG1,
                        u64* __restrict__ Wp81,
                        const float* __restrict__ z,
                        const float* __restrict__ Wg, const float* __restrict__ bg,
                        const float* __restrict__ Wb, const float* __restrict__ bb,
                        float* __restrict__ gamma, float* __restrict__ beta,
                        const float* __restrict__ bih0, const float* __restrict__ bhh0,
                        float* __restrict__ b01,
                        const float* __restrict__ bih1, const float* __restrict__ bhh1,
                        float* __restrict__ b11,
                        int* __restrict__ flags) {
  int i = blockIdx.x * blockDim.x + threadIdx.x;
  if (i < 8192) {
    packWg_body(Whh0, WpG0, i);
  } else if (i < 16384) {
    packWg_body(Whh1, WpG1, i - 8192);
  } else if (i < 40960) {
    packW8_body(Whh0, Wp80, i - 16384);
  } else if (i < 65536) {
    packW8_body(Whh1, Wp81, i - 40960);
  } else if (i < 73728) {
    int o = i - 65536;            // 8192: gamma|beta
    int which = o >> 12;
    int p = o & 4095;
    int b = p >> 8, h = p & 255;
    const float* W  = which ? Wb : Wg;
    const float* bi = which ? bb : bg;
    float acc = bi[h];
    const float* zr = z + b * 256;
    const float* wr = W + h * 256;
    #pragma unroll 8
    for (int k = 0; k < 256; k++) acc += zr[k] * wr[k];
    (which ? beta : gamma)[p] = acc;
  } else if (i < 74752) {
    int j = i - 73728;
    b01[j] = bih0[j] + bhh0[j];
  } else if (i < 75776) {
    int j = i - 74752;
    b11[j] = bih1[j] + bhh1[j];
  } else if (i < 77824) {
    flags[i - 75776] = 0;          // flagX..flagC, 2048 ints contiguous
  }
}

// ----------------------------- fused roles ---------------------------------

// gateAll: wait once for flagIn>=16 (X fully ready), then run fence-free.
static __device__ __forceinline__ void lstm_role(
    const float* __restrict__ Xpre, const u16* __restrict__ WpkG,
    const u64* __restrict__ Wpk8, u16* __restrict__ outb,
    const float* __restrict__ gamma, const float* __restrict__ beta,
    int mode, int s, int* flagOut, const int* flagIn, int gateAll,
    u16 (*hbuf)[256], u64 (*h8buf)[32]) {
  const int tid  = threadIdx.x;
  const int lane = tid & 63;
  const int w    = tid >> 6;
  const int l15  = lane & 15;
  const int lhi  = lane >> 4;

  short8 wgm[16];
  {
    const u16* bp = WpkG + ((size_t)(w * 16) * 64 + lane) * 8;
    #pragma unroll
    for (int f = 0; f < 16; ++f)
      wgm[f] = *(const short8*)(bp + (size_t)f * 512);
  }
  u64 w8r[48];
  {
    const u64* p8 = Wpk8 + (size_t)(w * 48) * 64 + lane;
    #pragma unroll
    for (int f = 0; f < 48; ++f)
      w8r[f] = p8[(size_t)f * 64];
  }

  const int col0 = w * 32 + l15;
  const int col1 = col0 + 16;
  float cs0 = 0.f, cs1 = 0.f;
  float gm0 = 1.f, gm1 = 1.f, bt0 = 0.f, bt1 = 0.f;
  if (mode) {
    gm0 = gamma[s * 256 + col0]; bt0 = beta[s * 256 + col0];
    gm1 = gamma[s * 256 + col1]; bt1 = beta[s * 256 + col1];
  }

  if (flagIn) {
    const int need0 = gateAll ? 16 : 1;
    if (tid == 0) {
      while (__hip_atomic_load(flagIn, __ATOMIC_RELAXED,
                               __HIP_MEMORY_SCOPE_AGENT) < need0) { }
    }
    __syncthreads();
    __builtin_amdgcn_fence(__ATOMIC_ACQUIRE, "agent");
  }

  const float* xptr = Xpre + (size_t)s * T_ * 1024 + (size_t)(w * 16 + l15) * 8;

  // ---- t = 0 ----
  f32x4 xa = *(const f32x4*)(xptr);
  f32x4 xg = *(const f32x4*)(xptr + 4);
  {
    float cn0 = sigf(xa[2]) * cs0 + sigf(xa[0]) * tanhfast(xg[0]);
    float hn0 = sigf(xg[2]) * tanhfast(cn0);
    cs0 = cn0;
    float cn1 = sigf(xa[3]) * cs1 + sigf(xa[1]) * tanhfast(xg[1]);
    float hn1 = sigf(xg[3]) * tanhfast(cn1);
    cs1 = cn1;
    u16 h0 = f2bf(hn0), h1 = f2bf(hn1);
    if (lhi == 0) {
      hbuf[0][col0] = h0;
      hbuf[0][col1] = h1;
      ((uint8_t*)h8buf[0])[col0] = (uint8_t)f32_to_e4m3(hn0);
      ((uint8_t*)h8buf[0])[col1] = (uint8_t)f32_to_e4m3(hn1);
      outb[(size_t)(s * T_) * 256 + col0] = mode ? f2bf(gm0 * hn0 + bt0) : h0;
      outb[(size_t)(s * T_) * 256 + col1] = mode ? f2bf(gm1 * hn1 + bt1) : h1;
    }
  }
  asm volatile("s_waitcnt lgkmcnt(0)" ::: "memory");
  __builtin_amdgcn_sched_barrier(0);
  __builtin_amdgcn_s_barrier();
  __builtin_amdgcn_sched_barrier(0);

  xa = *(const f32x4*)(xptr + 1024);
  xg = *(const f32x4*)(xptr + 1024 + 4);

  for (int t = 1; t < T_; ++t) {
    if (flagIn && !gateAll && (t & 15) == 15 && (t + 1) < T_) {
      const int need = ((t + 1) >> 4) + 1;
      if (tid == 0) {
        while (__hip_atomic_load(flagIn, __ATOMIC_RELAXED,
                                 __HIP_MEMORY_SCOPE_AGENT) < need) { }
      }
      __syncthreads();
      __builtin_amdgcn_fence(__ATOMIC_ACQUIRE, "agent");
    }

    const float* xn = xptr + (size_t)((t + 1 < T_) ? t + 1 : t) * 1024;
    f32x4 na = *(const f32x4*)(xn);
    f32x4 ng = *(const f32x4*)(xn + 4);

    const u16* hrd  = hbuf[(t + 1) & 1];
    const u64* h8rd = h8buf[(t + 1) & 1];

    f32x4 aI[2], aF[2], aG[2], aO[2];
    #pragma unroll
    for (int i = 0; i < 2; ++i) {
      aI[i] = (f32x4){0.f, 0.f, 0.f, 0.f};
      aF[i] = (f32x4){0.f, 0.f, 0.f, 0.f};
      aG[i] = (f32x4){0.f, 0.f, 0.f, 0.f};
      aO[i] = (f32x4){0.f, 0.f, 0.f, 0.f};
    }
    #pragma unroll
    for (int ks = 0; ks < 8; ++ks) {
      short8 a  = *(const short8*)&hrd[ks * 32 + lhi * 8];
      u64    a8 = h8rd[ks * 4 + lhi];
      aG[0] = __builtin_amdgcn_mfma_f32_16x16x32_bf16(a, wgm[ks],     aG[0], 0, 0, 0);
      aG[1] = __builtin_amdgcn_mfma_f32_16x16x32_bf16(a, wgm[8 + ks], aG[1], 0, 0, 0);
      aI[0] = __builtin_amdgcn_mfma_f32_16x16x32_fp8_fp8((long)a8, (long)w8r[ks],      aI[0], 0, 0, 0);
      aI[1] = __builtin_amdgcn_mfma_f32_16x16x32_fp8_fp8((long)a8, (long)w8r[8 + ks],  aI[1], 0, 0, 0);
      aF[0] = __builtin_amdgcn_mfma_f32_16x16x32_fp8_fp8((long)a8, (long)w8r[16 + ks], aF[0], 0, 0, 0);
      aF[1] = __builtin_amdgcn_mfma_f32_16x16x32_fp8_fp8((long)a8, (long)w8r[24 + ks], aF[1], 0, 0, 0);
      aO[0] = __builtin_amdgcn_mfma_f32_16x16x32_fp8_fp8((long)a8, (long)w8r[32 + ks], aO[0], 0, 0, 0);
      aO[1] = __builtin_amdgcn_mfma_f32_16x16x32_fp8_fp8((long)a8, (long)w8r[40 + ks], aO[1], 0, 0, 0);
    }

    float iv0 = aI[0][0] + xa[0], iv1 = aI[1][0] + xa[1];
    float fv0 = aF[0][0] + xa[2], fv1 = aF[1][0] + xa[3];
    float gv0 = aG[0][0] + xg[0], gv1 = aG[1][0] + xg[1];
    float ov0 = aO[0][0] + xg[2], ov1 = aO[1][0] + xg[3];

    float cn0 = sigf(fv0) * cs0 + sigf(iv0) * tanhfast(gv0);
    float hn0 = sigf(ov0) * tanhfast(cn0);
    cs0 = cn0;
    float cn1 = sigf(fv1) * cs1 + sigf(iv1) * tanhfast(gv1);
    float hn1 = sigf(ov1) * tanhfast(cn1);
    cs1 = cn1;

    u16 h0 = f2bf(hn0), h1 = f2bf(hn1);
    if (lhi == 0) {
      hbuf[t & 1][col0] = h0;
      hbuf[t & 1][col1] = h1;
      ((uint8_t*)h8buf[t & 1])[col0] = (uint8_t)f32_to_e4m3(hn0);
      ((uint8_t*)h8buf[t & 1])[col1] = (uint8_t)f32_to_e4m3(hn1);
      outb[((size_t)(s * T_ + t)) * 256 + col0] = mode ? f2bf(gm0 * hn0 + bt0) : h0;
      outb[((size_t)(s * T_ + t)) * 256 + col1] = mode ? f2bf(gm1 * hn1 + bt1) : h1;
    }

    if (flagOut && (t & 15) == 15) {
      __syncthreads();
      if (tid == 0) {
        __builtin_amdgcn_fence(__ATOMIC_RELEASE, "agent");
        __hip_atomic_store(flagOut, t + 1, __ATOMIC_RELAXED,
                           __HIP_MEMORY_SCOPE_AGENT);
      }
    } else {
      asm volatile("s_waitcnt lgkmcnt(0)" ::: "memory");
      __builtin_amdgcn_sched_barrier(0);
      __builtin_amdgcn_s_barrier();
      __builtin_amdgcn_sched_barrier(0);
    }

    xa = na;
    xg = ng;
  }
}

// gate-projection worker: dst(s, t0..t0+15, :) = src rows @ W^T + bias (permuted)
static __device__ __forceinline__ void proj_role(
    const u16* __restrict__ src, const u16* __restrict__ Wb_,
    const float* __restrict__ bias, float* __restrict__ dst,
    int s, const int* flagIn, int* flagOut) {
  const int tid  = threadIdx.x;
  const int lane = tid & 63;
  const int w    = tid >> 6;
  const int l15  = lane & 15;
  const int lhi  = lane >> 4;

  for (int tc = 0; tc < 16; ++tc) {
    if (flagIn) {
      const int need = (tc + 1) * 16;
      if (tid == 0) {
        while (__hip_atomic_load(flagIn, __ATOMIC_RELAXED,
                                 __HIP_MEMORY_SCOPE_AGENT) < need) { }
      }
      __syncthreads();
      __builtin_amdgcn_fence(__ATOMIC_ACQUIRE, "agent");
    }

    const int t0 = tc * 16;
    short8 afr[8];
    #pragma unroll
    for (int ks = 0; ks < 8; ++ks)
      afr[ks] = *(const short8*)(src + ((size_t)(s * T_ + t0 + l15)) * 256 + ks * 32 + lhi * 8);

    #pragma unroll
    for (int nt = 0; nt < 8; ++nt) {
      const int colb = w * 128 + nt * 16 + l15;
      f32x4 acc = (f32x4){0.f, 0.f, 0.f, 0.f};
      const u16* bp = Wb_ + (size_t)colb * 256 + lhi * 8;
      #pragma unroll
      for (int ks = 0; ks < 8; ++ks) {
        short8 bf = *(const short8*)(bp + ks * 32);
        acc = __builtin_amdgcn_mfma_f32_16x16x32_bf16(afr[ks], bf, acc, 0, 0, 0);
      }
      const int g = colb >> 8, r = colb & 255;
      const int ocol = (r >> 5) * 128 + (r & 15) * 8 + g * 2 + ((r >> 4) & 1);
      const float bv = bias[colb];
      #pragma unroll
      for (int i = 0; i < 4; ++i) {
        int trow = t0 + lhi * 4 + i;
        dst[((size_t)(s * T_ + trow)) * 1024 + ocol] = acc[i] + bv;
      }
    }

    __syncthreads();
    if (tid == 0) {
      __builtin_amdgcn_fence(__ATOMIC_RELEASE, "agent");
      __hip_atomic_store(flagOut, tc + 1, __ATOMIC_RELAXED,
                         __HIP_MEMORY_SCOPE_AGENT);
    }
  }
}

__global__ __launch_bounds__(LTPB, 2) void k_fused(
    const u16* __restrict__ xb, float* __restrict__ X0, float* __restrict__ X1,
    const u16* __restrict__ WpG0, const u64* __restrict__ Wp80,
    const u16* __restrict__ WpG1, const u64* __restrict__ Wp81,
    const u16* __restrict__ Wih0b, const float* __restrict__ b01,
    const u16* __restrict__ Wih1b, const float* __restrict__ b11,
    u16* __restrict__ h1b, u16* __restrict__ filmb,
    const float* __restrict__ gamma, const float* __restrict__ beta,
    int* __restrict__ flagX, int* __restrict__ flagA,
    int* __restrict__ flagB, int* __restrict__ flagC) {
  __shared__ __align__(16) char smem[1536];

  const int bid = blockIdx.x;
  if (bid < 16) {
    proj_role(xb, Wih0b, b01, X0, bid, nullptr, &flagX[bid * FSTR]);
  } else if (bid < 32) {
    const int s = bid - 16;
    lstm_role(X0, WpG0, Wp80, h1b, gamma, beta, 0, s,
              &flagA[s * FSTR], &flagX[s * FSTR], /*gateAll=*/1,
              (u16(*)[256])smem, (u64(*)[32])(smem + 1024));
  } else if (bid < 48) {
    const int s = bid - 32;
    proj_role(h1b, Wih1b, b11, X1, s, &flagA[s * FSTR], &flagB[s * FSTR]);
  } else {
    const int s = bid - 48;
    lstm_role(X1, WpG1, Wp81, filmb, gamma, beta, 1, s,
              &flagC[s * FSTR], &flagB[s * FSTR], /*gateAll=*/0,
              (u16(*)[256])smem, (u64(*)[32])(smem + 1024));
  }
}

// ------------------------- trailing vocab GEMM -----------------------------
// Tiles (M=64, N=128), m-tile-fastest order. A-tile staged ONCE in LDS
// (stride 264 u16 -> 2-way-free b128 reads; kills the 8x-redundant L2/LLC
// A-traffic). Epilogue: per-instruction wave-contiguous 512B stores.
__global__ __launch_bounds__(LTPB, 2) void k_vocab(
    const u16* __restrict__ filmb, const u16* __restrict__ Wo,
    const float* __restrict__ bout, float* __restrict__ out) {
  __shared__ u16   sA[64 * 264];     // 33 KB
  __shared__ float sC[64 * 132];     // 33.8 KB
  const int tid  = threadIdx.x;
  const int lane = tid & 63;
  const int w    = tid >> 6;
  const int l15  = lane & 15;
  const int lhi  = lane >> 4;

  for (int j = blockIdx.x; j < 16000; j += gridDim.x) {
    const int mt = j & 63;          // m-tile fastest
    const int nt = j >> 6;          // 0..249
    const int m0 = mt * 64;
    const int n0 = nt * 128;
    const int colb = n0 + w * 16 + l15;

    // stage A: 64 rows x 256 bf16; 8 threads/row x 4 short8 = 512B/row
    {
      const int r = tid >> 3, c = (tid & 7) * 32;
      const u16* srow = filmb + (size_t)(m0 + r) * 256 + c;
      #pragma unroll
      for (int k = 0; k < 4; ++k)
        *(short8*)&sA[r * 264 + c + k * 8] = *(const short8*)(srow + k * 8);
    }

    short8 bfr[8];
    #pragma unroll
    for (int ks = 0; ks < 8; ++ks)
      bfr[ks] = *(const short8*)(Wo + (size_t)colb * 256 + ks * 32 + lhi * 8);
    __syncthreads();

    f32x4 acc[4];
    #pragma unroll
    for (int mi = 0; mi < 4; ++mi) acc[mi] = (f32x4){0.f, 0.f, 0.f, 0.f};
    #pragma unroll
    for (int ks = 0; ks < 8; ++ks) {
      #pragma unroll
      for (int mi = 0; mi < 4; ++mi) {
        short8 a = *(const short8*)&sA[(mi * 16 + l15) * 264 + ks * 32 + lhi * 8];
        acc[mi] = __builtin_amdgcn_mfma_f32_16x16x32_bf16(a, bfr[ks], acc[mi], 0, 0, 0);
      }
    }

    const float bv = bout[colb];
    #pragma unroll
    for (int mi = 0; mi < 4; ++mi)
      #pragma unroll
      for (int i = 0; i < 4; ++i)
        sC[(mi * 16 + lhi * 4 + i) * 132 + w * 16 + l15] = acc[mi][i] + bv;
    __syncthreads();

    // wave w owns rows [w*8, w*8+8); lane l writes 8B at col l*2 ->
    // one instruction = 512B contiguous = 4 full cache lines.
    {
      const int rbase = w * 8;
      #pragma unroll
      for (int r = 0; r < 8; ++r) {
        const int row = rbase + r;
        f32x2 v;
        v[0] = sC[row * 132 + lane * 2];
        v[1] = sC[row * 132 + lane * 2 + 1];
        *(f32x2*)(out + (size_t)(m0 + row) * V_ + n0 + lane * 2) = v;
      }
    }
    __syncthreads();   // WAR: sA/sC reused next tile
  }
}

// ------------------------------ launcher -----------------------------------

extern "C" void kernel_launch(void* const* d_in, const int* in_sizes, int n_in,
                              void* d_out, int out_size, void* d_ws, size_t ws_size,
                              hipStream_t stream) {
  const float* z    = (const float*)d_in[0];
  const int*   seq  = (const int*)  d_in[1];
  const float* emb  = (const float*)d_in[2];
  const float* Wg   = (const float*)d_in[3];
  const float* bg   = (const float*)d_in[4];
  const float* Wb   = (const float*)d_in[5];
  const float* bb   = (const float*)d_in[6];
  const float* Wih0 = (const float*)d_in[7];
  const float* Whh0 = (const float*)d_in[8];
  const float* bih0 = (const float*)d_in[9];
  const float* bhh0 = (const float*)d_in[10];
  const float* Wih1 = (const float*)d_in[11];
  const float* Whh1 = (const float*)d_in[12];
  const float* bih1 = (const float*)d_in[13];
  const float* bhh1 = (const float*)d_in[14];
  const float* Wout = (const float*)d_in[15];
  const float* bout = (const float*)d_in[16];

  char* ws = (char*)d_ws;
  size_t off = 0;
  auto take = [&](size_t bytes) -> char* {
    char* p = ws + off;
    off = (off + bytes + 255) & ~(size_t)255;
    return p;
  };
  float* gamma  = (float*)take(B_ * H_ * 4);
  float* beta   = (float*)take(B_ * H_ * 4);
  float* b01    = (float*)take(G4 * 4);
  float* b11    = (float*)take(G4 * 4);
  u16*   Wih0b  = (u16*)  take((size_t)G4 * H_ * 2);
  u16*   Wih1b  = (u16*)  take((size_t)G4 * H_ * 2);
  u16*   WpG0   = (u16*)  take((size_t)8 * 16 * 64 * 8 * 2);
  u64*   Wp80   = (u64*)  take((size_t)8 * 48 * 64 * 8);
  u16*   WpG1   = (u16*)  take((size_t)8 * 16 * 64 * 8 * 2);
  u64*   Wp81   = (u64*)  take((size_t)8 * 48 * 64 * 8);
  u16*   Woutb  = (u16*)  take((size_t)V_ * H_ * 2);
  u16*   xb     = (u16*)  take((size_t)B_ * T_ * H_ * 2);
  float* X0     = (float*)take((size_t)B_ * T_ * G4 * 4);
  float* X1     = (float*)take((size_t)B_ * T_ * G4 * 4);
  u16*   h1b    = (u16*)  take((size_t)B_ * T_ * H_ * 2);
  u16*   filmb  = (u16*)  take((size_t)B_ * T_ * H_ * 2);
  int*   flagX  = (int*)  take(B_ * FSTR * 4);
  int*   flagA  = (int*)  take(B_ * FSTR * 4);
  int*   flagB  = (int*)  take(B_ * FSTR * 4);
  int*   flagC  = (int*)  take(B_ * FSTR * 4);
  (void)ws_size; (void)in_sizes; (void)n_in; (void)out_size;

  // prep: 2 launches
  k_prepA<<<4096, 256, 0, stream>>>(Wih0, Wih0b, Wih1, Wih1b, Wout, Woutb,
                                    seq, emb, xb);
  k_prepB<<<304, 256, 0, stream>>>(Whh0, WpG0, Wp80, Whh1, WpG1, Wp81,
                                   z, Wg, bg, Wb, bb, gamma, beta,
                                   bih0, bhh0, b01, bih1, bhh1, b11, flagX);

  // fused pipeline: X0proj || L0 || X1proj || L1  (64 blocks)
  k_fused<<<64, LTPB, 0, stream>>>(
      xb, X0, X1, WpG0, Wp80, WpG1, Wp81, Wih0b, b01, Wih1b, b11,
      h1b, filmb, gamma, beta, flagX, flagA, flagB, flagC);

  // trailing vocab GEMM (LDS-staged A + full-line epilogue)
  k_vocab<<<1024, LTPB, 0, stream>>>(filmb, Woutb, bout, (float*)d_out);
}

// Round 18
// 769.831 us; speedup vs baseline: 1.4868x; 1.2451x over previous
//
#include <hip/hip_runtime.h>
#include <stdint.h>

// ---------------------------------------------------------------------------
// ConditionalDecoder: emb-gather -> LSTM x2 -> FiLM -> vocab GEMM
// B=16, T=256, V=32000, E=H=Z=256, 4H=1024
// Round 18: consolidation of proven-best pieces.
//   - X0: separate WIDE k_gemm_bt dispatch (256 blocks, ~30us, permX) --
//     dispatch boundary = free acquire; L0 runs fence-free (r11-proven).
//   - k_fused (48 blocks): L0 || X1proj || L1. L1 no longer signals
//     (flagC had no consumer) -> saves 16 release drains.
//   - k_vocab: LDS-staged A + full-line 512B epilogue (r17-proven).
//   - prep: 2 grid-stride launches.
// ---------------------------------------------------------------------------

#define B_  16
#define T_  256
#define H_  256
#define V_  32000
#define G4  1024

#define LTPB 512   // 8 waves
#define FSTR 32    // flag stride in ints (one 128B line per flag)

typedef unsigned short u16;
typedef unsigned long long u64;
typedef __attribute__((ext_vector_type(8))) short  short8;
typedef __attribute__((ext_vector_type(4))) short  short4v;
typedef __attribute__((ext_vector_type(4))) float  f32x4;
typedef __attribute__((ext_vector_type(2))) float  f32x2;

static __device__ __forceinline__ float bf2f(u16 u) {
  uint32_t i = ((uint32_t)u) << 16;
  return __builtin_bit_cast(float, i);
}
static __device__ __forceinline__ u16 f2bf(float f) {
  uint32_t i = __builtin_bit_cast(uint32_t, f);
  uint32_t lsb = (i >> 16) & 1u;
  i += 0x7fffu + lsb;
  return (u16)(i >> 16);
}
static __device__ __forceinline__ float sigf(float x) {
  return 1.0f / (1.0f + __expf(-x));
}
static __device__ __forceinline__ float tanhfast(float x) {
  return 1.0f - 2.0f / (1.0f + __expf(2.0f * x));
}

// OCP e4m3fn encode (bias 7, max 448, RNE). Same encoder for W-pack and h.
static __device__ __forceinline__ uint32_t f32_to_e4m3(float f) {
  uint32_t u = __builtin_bit_cast(uint32_t, f);
  uint32_t s = (u >> 24) & 0x80u;
  uint32_t mag = u & 0x7fffffffu;
  if (mag >= 0x43E00000u) return s | 0x7Eu;
  if (mag < 0x3C800000u) {
    float af = __builtin_bit_cast(float, mag);
    int q = (int)rintf(af * 512.0f);
    if (q >= 8) return s | 0x08u;
    return s | (uint32_t)q;
  }
  uint32_t lsb = (mag >> 20) & 1u;
  mag += 0x7ffffu + lsb;
  int e = (int)(mag >> 23) - 120;
  uint32_t m3 = (mag >> 20) & 7u;
  if (e >= 16) return s | 0x7Eu;
  return s | ((uint32_t)e << 3) | m3;
}

// ------------------------------ prep kernels -------------------------------

// All bf16 converts + embedding gather, one grid-stride kernel.
__global__ void k_prepA(const float* __restrict__ Wih0, u16* __restrict__ Wih0b,
                        const float* __restrict__ Wih1, u16* __restrict__ Wih1b,
                        const float* __restrict__ Wout, u16* __restrict__ Woutb,
                        const int* __restrict__ seq, const float* __restrict__ emb,
                        u16* __restrict__ xb) {
  const int N1 = G4 * H_;                    // 262144
  const int N2 = N1 + G4 * H_;               // 524288
  const int N3 = N2 + V_ * H_;               // 8716288
  const int N4 = N3 + B_ * T_ * (H_ / 4);    // 8978432
  int stride = gridDim.x * blockDim.x;
  for (int i = blockIdx.x * blockDim.x + threadIdx.x; i < N4; i += stride) {
    if (i < N1) {
      Wih0b[i] = f2bf(Wih0[i]);
    } else if (i < N2) {
      int j = i - N1;
      Wih1b[j] = f2bf(Wih1[j]);
    } else if (i < N3) {
      int j = i - N2;
      Woutb[j] = f2bf(Wout[j]);
    } else {
      int j = i - N3;
      int e4 = j & 63, bt = j >> 6;
      int t = bt & 255, b = bt >> 8;
      int row = seq[b * 257 + t];
      short4v p;
      if (row == 0) {
        p[0] = 0; p[1] = 0; p[2] = 0; p[3] = 0;
      } else {
        f32x4 v = *(const f32x4*)(emb + (size_t)row * 256 + e4 * 4);
        p[0] = (short)f2bf(v[0]); p[1] = (short)f2bf(v[1]);
        p[2] = (short)f2bf(v[2]); p[3] = (short)f2bf(v[3]);
      }
      *(short4v*)(xb + (size_t)bt * 256 + e4 * 4) = p;
    }
  }
}

static __device__ __forceinline__ void packWg_body(
    const float* __restrict__ Whh, u16* __restrict__ pk, int i) {
  int lane = i & 63;
  int fb = (i >> 6) & 15;
  int w  = i >> 10;
  int cb = fb >> 3, ks = fb & 7;
  int row = 512 + w * 32 + cb * 16 + (lane & 15);
  int kb  = ks * 32 + (lane >> 4) * 8;
  const float* src = Whh + (size_t)row * 256 + kb;
  short8 v;
  #pragma unroll
  for (int j = 0; j < 8; j++) v[j] = (short)f2bf(src[j]);
  *(short8*)(pk + (size_t)i * 8) = v;
}

static __device__ __forceinline__ void packW8_body(
    const float* __restrict__ Whh, u64* __restrict__ pk, int i) {
  int lane = i & 63;
  int fo = (i >> 6) % 48;
  int w  = (i >> 6) / 48;
  int g8 = fo >> 4, cb = (fo >> 3) & 1, ks = fo & 7;
  int base = (g8 == 0) ? 0 : (g8 == 1 ? 256 : 768);
  int row = base + w * 32 + cb * 16 + (lane & 15);
  int kb  = ks * 32 + (lane >> 4) * 8;
  const float* src = Whh + (size_t)row * 256 + kb;
  u64 p = 0;
  #pragma unroll
  for (int j = 0; j < 8; j++)
    p |= ((u64)f32_to_e4m3(src[j])) << (8 * j);
  pk[i] = p;
}

// W_hh packs + FiLM + bias sums + flag zeroing (304 blocks x 256).
__global__ void k_prepB(const float* __restrict__ Whh0, u16* __restrict__ WpG0,
                        u64* __restrict__ Wp80,
                        const float* __restrict__ Whh1, u16* __restrict__ WpG1,
                        u64* __restrict__ Wp81,
                        const float* __restrict__ z,
                        const float* __restrict__ Wg, const float* __restrict__ bg,
                        const float* __restrict__ Wb, const float* __restrict__ bb,
                        float* __restrict__ gamma, float* __restrict__ beta,
                        const float* __restrict__ bih0, const float* __restrict__ bhh0,
                        float* __restrict__ b01,
                        const float* __restrict__ bih1, const float* __restrict__ bhh1,
                        float* __restrict__ b11,
                        int* __restrict__ flags) {
  int i = blockIdx.x * blockDim.x + threadIdx.x;
  if (i < 8192) {
    packWg_body(Whh0, WpG0, i);
  } else if (i < 16384) {
    packWg_body(Whh1, WpG1, i - 8192);
  } else if (i < 40960) {
    packW8_body(Whh0, Wp80, i - 16384);
  } else if (i < 65536) {
    packW8_body(Whh1, Wp81, i - 40960);
  } else if (i < 73728) {
    int o = i - 65536;            // 8192: gamma|beta
    int which = o >> 12;
    int p = o & 4095;
    int b = p >> 8, h = p & 255;
    const float* W  = which ? Wb : Wg;
    const float* bi = which ? bb : bg;
    float acc = bi[h];
    const float* zr = z + b * 256;
    const float* wr = W + h * 256;
    #pragma unroll 8
    for (int k = 0; k < 256; k++) acc += zr[k] * wr[k];
    (which ? beta : gamma)[p] = acc;
  } else if (i < 74752) {
    int j = i - 73728;
    b01[j] = bih0[j] + bhh0[j];
  } else if (i < 75776) {
    int j = i - 74752;
    b11[j] = bih1[j] + bhh1[j];
  } else if (i < 77824) {
    flags[i - 75776] = 0;          // flags, 2048 ints contiguous
  }
}

// ------------------------------ bf16 GEMM (X0) -----------------------------
// C(M,N) fp32 = A(M,K)bf16 @ B(N,K)bf16^T + bias(N), permuted X layout:
// col = g*256 + r -> ocol = (r>>5)*128 + (r&15)*8 + g*2 + ((r>>4)&1).

__global__ __launch_bounds__(256) void k_gemm_bt(
    const u16* __restrict__ A, const u16* __restrict__ Bm,
    const float* __restrict__ bias, float* __restrict__ C,
    int M, int N, int K) {
  __shared__ u16 sA[128 * 40];
  __shared__ u16 sB[128 * 40];
  const int tid  = threadIdx.x;
  const int lane = tid & 63;
  const int wv   = tid >> 6;
  const int wr   = wv >> 1, wc = wv & 1;
  const int m0 = blockIdx.y * 128, n0 = blockIdx.x * 128;
  const int rr = tid >> 2;
  const int cc = (tid & 3) * 8;

  f32x4 acc[4][4];
  #pragma unroll
  for (int m = 0; m < 4; m++)
    #pragma unroll
    for (int n = 0; n < 4; n++) acc[m][n] = (f32x4){0.f, 0.f, 0.f, 0.f};

  for (int ks = 0; ks < K; ks += 32) {
    short8 va0 = *(const short8*)(A  + (size_t)(m0 + rr)      * K + ks + cc);
    short8 va1 = *(const short8*)(A  + (size_t)(m0 + rr + 64) * K + ks + cc);
    short8 vb0 = *(const short8*)(Bm + (size_t)(n0 + rr)      * K + ks + cc);
    short8 vb1 = *(const short8*)(Bm + (size_t)(n0 + rr + 64) * K + ks + cc);
    __syncthreads();
    *(short8*)&sA[(rr)      * 40 + cc] = va0;
    *(short8*)&sA[(rr + 64) * 40 + cc] = va1;
    *(short8*)&sB[(rr)      * 40 + cc] = vb0;
    *(short8*)&sB[(rr + 64) * 40 + cc] = vb1;
    __syncthreads();
    const int kc = (lane >> 4) * 8;
    short8 af[4], bfr[4];
    #pragma unroll
    for (int m = 0; m < 4; m++)
      af[m] = *(const short8*)&sA[(wr * 64 + m * 16 + (lane & 15)) * 40 + kc];
    #pragma unroll
    for (int n = 0; n < 4; n++)
      bfr[n] = *(const short8*)&sB[(wc * 64 + n * 16 + (lane & 15)) * 40 + kc];
    #pragma unroll
    for (int m = 0; m < 4; m++)
      #pragma unroll
      for (int n = 0; n < 4; n++)
        acc[m][n] = __builtin_amdgcn_mfma_f32_16x16x32_bf16(af[m], bfr[n], acc[m][n], 0, 0, 0);
  }

  #pragma unroll
  for (int m = 0; m < 4; m++) {
    int row = m0 + wr * 64 + m * 16 + ((lane >> 4) << 2);
    #pragma unroll
    for (int n = 0; n < 4; n++) {
      int col = n0 + wc * 64 + n * 16 + (lane & 15);
      float bv = bias[col];
      int g = col >> 8, r = col & 255;
      int ocol = (r >> 5) * 128 + (r & 15) * 8 + g * 2 + ((r >> 4) & 1);
      #pragma unroll
      for (int i = 0; i < 4; i++)
        C[(size_t)(row + i) * N + ocol] = acc[m][n][i] + bv;
    }
  }
}

// ----------------------------- fused roles ---------------------------------

static __device__ __forceinline__ void lstm_role(
    const float* __restrict__ Xpre, const u16* __restrict__ WpkG,
    const u64* __restrict__ Wpk8, u16* __restrict__ outb,
    const float* __restrict__ gamma, const float* __restrict__ beta,
    int mode, int s, int* flagOut, const int* flagIn,
    u16 (*hbuf)[256], u64 (*h8buf)[32]) {
  const int tid  = threadIdx.x;
  const int lane = tid & 63;
  const int w    = tid >> 6;
  const int l15  = lane & 15;
  const int lhi  = lane >> 4;

  short8 wgm[16];
  {
    const u16* bp = WpkG + ((size_t)(w * 16) * 64 + lane) * 8;
    #pragma unroll
    for (int f = 0; f < 16; ++f)
      wgm[f] = *(const short8*)(bp + (size_t)f * 512);
  }
  u64 w8r[48];
  {
    const u64* p8 = Wpk8 + (size_t)(w * 48) * 64 + lane;
    #pragma unroll
    for (int f = 0; f < 48; ++f)
      w8r[f] = p8[(size_t)f * 64];
  }

  const int col0 = w * 32 + l15;
  const int col1 = col0 + 16;
  float cs0 = 0.f, cs1 = 0.f;
  float gm0 = 1.f, gm1 = 1.f, bt0 = 0.f, bt1 = 0.f;
  if (mode) {
    gm0 = gamma[s * 256 + col0]; bt0 = beta[s * 256 + col0];
    gm1 = gamma[s * 256 + col1]; bt1 = beta[s * 256 + col1];
  }

  if (flagIn) {
    if (tid == 0) {
      while (__hip_atomic_load(flagIn, __ATOMIC_RELAXED,
                               __HIP_MEMORY_SCOPE_AGENT) < 1) { }
    }
    __syncthreads();
    __builtin_amdgcn_fence(__ATOMIC_ACQUIRE, "agent");
  }

  const float* xptr = Xpre + (size_t)s * T_ * 1024 + (size_t)(w * 16 + l15) * 8;

  // ---- t = 0 ----
  f32x4 xa = *(const f32x4*)(xptr);
  f32x4 xg = *(const f32x4*)(xptr + 4);
  {
    float cn0 = sigf(xa[2]) * cs0 + sigf(xa[0]) * tanhfast(xg[0]);
    float hn0 = sigf(xg[2]) * tanhfast(cn0);
    cs0 = cn0;
    float cn1 = sigf(xa[3]) * cs1 + sigf(xa[1]) * tanhfast(xg[1]);
    float hn1 = sigf(xg[3]) * tanhfast(cn1);
    cs1 = cn1;
    u16 h0 = f2bf(hn0), h1 = f2bf(hn1);
    if (lhi == 0) {
      hbuf[0][col0] = h0;
      hbuf[0][col1] = h1;
      ((uint8_t*)h8buf[0])[col0] = (uint8_t)f32_to_e4m3(hn0);
      ((uint8_t*)h8buf[0])[col1] = (uint8_t)f32_to_e4m3(hn1);
      outb[(size_t)(s * T_) * 256 + col0] = mode ? f2bf(gm0 * hn0 + bt0) : h0;
      outb[(size_t)(s * T_) * 256 + col1] = mode ? f2bf(gm1 * hn1 + bt1) : h1;
    }
  }
  asm volatile("s_waitcnt lgkmcnt(0)" ::: "memory");
  __builtin_amdgcn_sched_barrier(0);
  __builtin_amdgcn_s_barrier();
  __builtin_amdgcn_sched_barrier(0);

  xa = *(const f32x4*)(xptr + 1024);
  xg = *(const f32x4*)(xptr + 1024 + 4);

  for (int t = 1; t < T_; ++t) {
    if (flagIn && (t & 15) == 15 && (t + 1) < T_) {
      const int need = ((t + 1) >> 4) + 1;
      if (tid == 0) {
        while (__hip_atomic_load(flagIn, __ATOMIC_RELAXED,
                                 __HIP_MEMORY_SCOPE_AGENT) < need) { }
      }
      __syncthreads();
      __builtin_amdgcn_fence(__ATOMIC_ACQUIRE, "agent");
    }

    const float* xn = xptr + (size_t)((t + 1 < T_) ? t + 1 : t) * 1024;
    f32x4 na = *(const f32x4*)(xn);
    f32x4 ng = *(const f32x4*)(xn + 4);

    const u16* hrd  = hbuf[(t + 1) & 1];
    const u64* h8rd = h8buf[(t + 1) & 1];

    f32x4 aI[2], aF[2], aG[2], aO[2];
    #pragma unroll
    for (int i = 0; i < 2; ++i) {
      aI[i] = (f32x4){0.f, 0.f, 0.f, 0.f};
      aF[i] = (f32x4){0.f, 0.f, 0.f, 0.f};
      aG[i] = (f32x4){0.f, 0.f, 0.f, 0.f};
      aO[i] = (f32x4){0.f, 0.f, 0.f, 0.f};
    }
    #pragma unroll
    for (int ks = 0; ks < 8; ++ks) {
      short8 a  = *(const short8*)&hrd[ks * 32 + lhi * 8];
      u64    a8 = h8rd[ks * 4 + lhi];
      aG[0] = __builtin_amdgcn_mfma_f32_16x16x32_bf16(a, wgm[ks],     aG[0], 0, 0, 0);
      aG[1] = __builtin_amdgcn_mfma_f32_16x16x32_bf16(a, wgm[8 + ks], aG[1], 0, 0, 0);
      aI[0] = __builtin_amdgcn_mfma_f32_16x16x32_fp8_fp8((long)a8, (long)w8r[ks],      aI[0], 0, 0, 0);
      aI[1] = __builtin_amdgcn_mfma_f32_16x16x32_fp8_fp8((long)a8, (long)w8r[8 + ks],  aI[1], 0, 0, 0);
      aF[0] = __builtin_amdgcn_mfma_f32_16x16x32_fp8_fp8((long)a8, (long)w8r[16 + ks], aF[0], 0, 0, 0);
      aF[1] = __builtin_amdgcn_mfma_f32_16x16x32_fp8_fp8((long)a8, (long)w8r[24 + ks], aF[1], 0, 0, 0);
      aO[0] = __builtin_amdgcn_mfma_f32_16x16x32_fp8_fp8((long)a8, (long)w8r[32 + ks], aO[0], 0, 0, 0);
      aO[1] = __builtin_amdgcn_mfma_f32_16x16x32_fp8_fp8((long)a8, (long)w8r[40 + ks], aO[1], 0, 0, 0);
    }

    float iv0 = aI[0][0] + xa[0], iv1 = aI[1][0] + xa[1];
    float fv0 = aF[0][0] + xa[2], fv1 = aF[1][0] + xa[3];
    float gv0 = aG[0][0] + xg[0], gv1 = aG[1][0] + xg[1];
    float ov0 = aO[0][0] + xg[2], ov1 = aO[1][0] + xg[3];

    float cn0 = sigf(fv0) * cs0 + sigf(iv0) * tanhfast(gv0);
    float hn0 = sigf(ov0) * tanhfast(cn0);
    cs0 = cn0;
    float cn1 = sigf(fv1) * cs1 + sigf(iv1) * tanhfast(gv1);
    float hn1 = sigf(ov1) * tanhfast(cn1);
    cs1 = cn1;

    u16 h0 = f2bf(hn0), h1 = f2bf(hn1);
    if (lhi == 0) {
      hbuf[t & 1][col0] = h0;
      hbuf[t & 1][col1] = h1;
      ((uint8_t*)h8buf[t & 1])[col0] = (uint8_t)f32_to_e4m3(hn0);
      ((uint8_t*)h8buf[t & 1])[col1] = (uint8_t)f32_to_e4m3(hn1);
      outb[((size_t)(s * T_ + t)) * 256 + col0] = mode ? f2bf(gm0 * hn0 + bt0) : h0;
      outb[((size_t)(s * T_ + t)) * 256 + col1] = mode ? f2bf(gm1 * hn1 + bt1) : h1;
    }

    if (flagOut && (t & 15) == 15) {
      __syncthreads();
      if (tid == 0) {
        __builtin_amdgcn_fence(__ATOMIC_RELEASE, "agent");
        __hip_atomic_store(flagOut, t + 1, __ATOMIC_RELAXED,
                           __HIP_MEMORY_SCOPE_AGENT);
      }
    } else {
      asm volatile("s_waitcnt lgkmcnt(0)" ::: "memory");
      __builtin_amdgcn_sched_barrier(0);
      __builtin_amdgcn_s_barrier();
      __builtin_amdgcn_sched_barrier(0);
    }

    xa = na;
    xg = ng;
  }
}

// gate-projection worker: dst(s, t0..t0+15, :) = src rows @ W^T + bias (permuted)
static __device__ __forceinline__ void proj_role(
    const u16* __restrict__ src, const u16* __restrict__ Wb_,
    const float* __restrict__ bias, float* __restrict__ dst,
    int s, const int* flagIn, int* flagOut) {
  const int tid  = threadIdx.x;
  const int lane = tid & 63;
  const int w    = tid >> 6;
  const int l15  = lane & 15;
  const int lhi  = lane >> 4;

  for (int tc = 0; tc < 16; ++tc) {
    if (flagIn) {
      const int need = (tc + 1) * 16;
      if (tid == 0) {
        while (__hip_atomic_load(flagIn, __ATOMIC_RELAXED,
                                 __HIP_MEMORY_SCOPE_AGENT) < need) { }
      }
      __syncthreads();
      __builtin_amdgcn_fence(__ATOMIC_ACQUIRE, "agent");
    }

    const int t0 = tc * 16;
    short8 afr[8];
    #pragma unroll
    for (int ks = 0; ks < 8; ++ks)
      afr[ks] = *(const short8*)(src + ((size_t)(s * T_ + t0 + l15)) * 256 + ks * 32 + lhi * 8);

    #pragma unroll
    for (int nt = 0; nt < 8; ++nt) {
      const int colb = w * 128 + nt * 16 + l15;
      f32x4 acc = (f32x4){0.f, 0.f, 0.f, 0.f};
      const u16* bp = Wb_ + (size_t)colb * 256 + lhi * 8;
      #pragma unroll
      for (int ks = 0; ks < 8; ++ks) {
        short8 bf = *(const short8*)(bp + ks * 32);
        acc = __builtin_amdgcn_mfma_f32_16x16x32_bf16(afr[ks], bf, acc, 0, 0, 0);
      }
      const int g = colb >> 8, r = colb & 255;
      const int ocol = (r >> 5) * 128 + (r & 15) * 8 + g * 2 + ((r >> 4) & 1);
      const float bv = bias[colb];
      #pragma unroll
      for (int i = 0; i < 4; ++i) {
        int trow = t0 + lhi * 4 + i;
        dst[((size_t)(s * T_ + trow)) * 1024 + ocol] = acc[i] + bv;
      }
    }

    __syncthreads();
    if (tid == 0) {
      __builtin_amdgcn_fence(__ATOMIC_RELEASE, "agent");
      __hip_atomic_store(flagOut, tc + 1, __ATOMIC_RELAXED,
                         __HIP_MEMORY_SCOPE_AGENT);
    }
  }
}

__global__ __launch_bounds__(LTPB, 2) void k_fused(
    float* __restrict__ X0, float* __restrict__ X1,
    const u16* __restrict__ WpG0, const u64* __restrict__ Wp80,
    const u16* __restrict__ WpG1, const u64* __restrict__ Wp81,
    const u16* __restrict__ Wih1b, const float* __restrict__ b11,
    u16* __restrict__ h1b, u16* __restrict__ filmb,
    const float* __restrict__ gamma, const float* __restrict__ beta,
    int* __restrict__ flagA, int* __restrict__ flagB) {
  __shared__ __align__(16) char smem[1536];

  const int bid = blockIdx.x;
  if (bid < 16) {
    // L0: X0 fully materialized by the preceding dispatch -> fence-free.
    lstm_role(X0, WpG0, Wp80, h1b, gamma, beta, 0, bid,
              &flagA[bid * FSTR], nullptr,
              (u16(*)[256])smem, (u64(*)[32])(smem + 1024));
  } else if (bid < 32) {
    const int s = bid - 16;
    proj_role(h1b, Wih1b, b11, X1, s, &flagA[s * FSTR], &flagB[s * FSTR]);
  } else {
    const int s = bid - 32;
    lstm_role(X1, WpG1, Wp81, filmb, gamma, beta, 1, s,
              nullptr, &flagB[s * FSTR],
              (u16(*)[256])smem, (u64(*)[32])(smem + 1024));
  }
}

// ------------------------- trailing vocab GEMM -----------------------------
// Tiles (M=64, N=128), m-tile-fastest. A-tile staged once in LDS (stride 264
// -> 2-way-free b128 reads). Epilogue: wave-contiguous 512B full-line stores.
__global__ __launch_bounds__(LTPB, 2) void k_vocab(
    const u16* __restrict__ filmb, const u16* __restrict__ Wo,
    const float* __restrict__ bout, float* __restrict__ out) {
  __shared__ u16   sA[64 * 264];
  __shared__ float sC[64 * 132];
  const int tid  = threadIdx.x;
  const int lane = tid & 63;
  const int w    = tid >> 6;
  const int l15  = lane & 15;
  const int lhi  = lane >> 4;

  for (int j = blockIdx.x; j < 16000; j += gridDim.x) {
    const int mt = j & 63;
    const int nt = j >> 6;
    const int m0 = mt * 64;
    const int n0 = nt * 128;
    const int colb = n0 + w * 16 + l15;

    {
      const int r = tid >> 3, c = (tid & 7) * 32;
      const u16* srow = filmb + (size_t)(m0 + r) * 256 + c;
      #pragma unroll
      for (int k = 0; k < 4; ++k)
        *(short8*)&sA[r * 264 + c + k * 8] = *(const short8*)(srow + k * 8);
    }

    short8 bfr[8];
    #pragma unroll
    for (int ks = 0; ks < 8; ++ks)
      bfr[ks] = *(const short8*)(Wo + (size_t)colb * 256 + ks * 32 + lhi * 8);
    __syncthreads();

    f32x4 acc[4];
    #pragma unroll
    for (int mi = 0; mi < 4; ++mi) acc[mi] = (f32x4){0.f, 0.f, 0.f, 0.f};
    #pragma unroll
    for (int ks = 0; ks < 8; ++ks) {
      #pragma unroll
      for (int mi = 0; mi < 4; ++mi) {
        short8 a = *(const short8*)&sA[(mi * 16 + l15) * 264 + ks * 32 + lhi * 8];
        acc[mi] = __builtin_amdgcn_mfma_f32_16x16x32_bf16(a, bfr[ks], acc[mi], 0, 0, 0);
      }
    }

    const float bv = bout[colb];
    #pragma unroll
    for (int mi = 0; mi < 4; ++mi)
      #pragma unroll
      for (int i = 0; i < 4; ++i)
        sC[(mi * 16 + lhi * 4 + i) * 132 + w * 16 + l15] = acc[mi][i] + bv;
    __syncthreads();

    {
      const int rbase = w * 8;
      #pragma unroll
      for (int r = 0; r < 8; ++r) {
        const int row = rbase + r;
        f32x2 v;
        v[0] = sC[row * 132 + lane * 2];
        v[1] = sC[row * 132 + lane * 2 + 1];
        *(f32x2*)(out + (size_t)(m0 + row) * V_ + n0 + lane * 2) = v;
      }
    }
    __syncthreads();
  }
}

// ------------------------------ launcher -----------------------------------

extern "C" void kernel_launch(void* const* d_in, const int* in_sizes, int n_in,
                              void* d_out, int out_size, void* d_ws, size_t ws_size,
                              hipStream_t stream) {
  const float* z    = (const float*)d_in[0];
  const int*   seq  = (const int*)  d_in[1];
  const float* emb  = (const float*)d_in[2];
  const float* Wg   = (const float*)d_in[3];
  const float* bg   = (const float*)d_in[4];
  const float* Wb   = (const float*)d_in[5];
  const float* bb   = (const float*)d_in[6];
  const float* Wih0 = (const float*)d_in[7];
  const float* Whh0 = (const float*)d_in[8];
  const float* bih0 = (const float*)d_in[9];
  const float* bhh0 = (const float*)d_in[10];
  const float* Wih1 = (const float*)d_in[11];
  const float* Whh1 = (const float*)d_in[12];
  const float* bih1 = (const float*)d_in[13];
  const float* bhh1 = (const float*)d_in[14];
  const float* Wout = (const float*)d_in[15];
  const float* bout = (const float*)d_in[16];

  char* ws = (char*)d_ws;
  size_t off = 0;
  auto take = [&](size_t bytes) -> char* {
    char* p = ws + off;
    off = (off + bytes + 255) & ~(size_t)255;
    return p;
  };
  float* gamma  = (float*)take(B_ * H_ * 4);
  float* beta   = (float*)take(B_ * H_ * 4);
  float* b01    = (float*)take(G4 * 4);
  float* b11    = (float*)take(G4 * 4);
  u16*   Wih0b  = (u16*)  take((size_t)G4 * H_ * 2);
  u16*   Wih1b  = (u16*)  take((size_t)G4 * H_ * 2);
  u16*   WpG0   = (u16*)  take((size_t)8 * 16 * 64 * 8 * 2);
  u64*   Wp80   = (u64*)  take((size_t)8 * 48 * 64 * 8);
  u16*   WpG1   = (u16*)  take((size_t)8 * 16 * 64 * 8 * 2);
  u64*   Wp81   = (u64*)  take((size_t)8 * 48 * 64 * 8);
  u16*   Woutb  = (u16*)  take((size_t)V_ * H_ * 2);
  u16*   xb     = (u16*)  take((size_t)B_ * T_ * H_ * 2);
  float* X0     = (float*)take((size_t)B_ * T_ * G4 * 4);
  float* X1     = (float*)take((size_t)B_ * T_ * G4 * 4);
  u16*   h1b    = (u16*)  take((size_t)B_ * T_ * H_ * 2);
  u16*   filmb  = (u16*)  take((size_t)B_ * T_ * H_ * 2);
  int*   flagA  = (int*)  take(B_ * FSTR * 4);
  int*   flagB  = (int*)  take(B_ * FSTR * 4);
  (void)ws_size; (void)in_sizes; (void)n_in; (void)out_size;

  // prep: 2 launches
  k_prepA<<<4096, 256, 0, stream>>>(Wih0, Wih0b, Wih1, Wih1b, Wout, Woutb,
                                    seq, emb, xb);
  k_prepB<<<304, 256, 0, stream>>>(Whh0, WpG0, Wp80, Whh1, WpG1, Wp81,
                                   z, Wg, bg, Wb, bb, gamma, beta,
                                   bih0, bhh0, b01, bih1, bhh1, b11, flagA);

  // X0 projection: wide dispatch (fast); boundary = free acquire for L0
  k_gemm_bt<<<dim3(G4 / 128, (B_ * T_) / 128), 256, 0, stream>>>(
      xb, Wih0b, b01, X0, B_ * T_, G4, H_);

  // fused pipeline: L0 || X1proj || L1  (48 blocks)
  k_fused<<<48, LTPB, 0, stream>>>(
      X0, X1, WpG0, Wp80, WpG1, Wp81, Wih1b, b11,
      h1b, filmb, gamma, beta, flagA, flagB);

  // trailing vocab GEMM (LDS-staged A + full-line epilogue)
  k_vocab<<<1024, LTPB, 0, stream>>>(filmb, Woutb, bout, (float*)d_out);
}

// Round 19
// 754.240 us; speedup vs baseline: 1.5176x; 1.0207x over previous
//
#include <hip/hip_runtime.h>
#include <stdint.h>

// ---------------------------------------------------------------------------
// ConditionalDecoder: emb-gather -> LSTM x2 -> FiLM -> vocab GEMM
// B=16, T=256, V=32000, E=H=Z=256, 4H=1024
// Round 19: final consolidation on the r18 structure (769us).
//   - k_prep: prepA+prepB merged into ONE dispatch (prepB items on the
//     first 77824 threads, prepA grid-strided) -- one less launch gap.
//   - k_vocab: 2000 blocks = exactly 8 tiles each (no tail imbalance);
//     XCD-chunked tile mapping so CUs on one XCD share Wo column groups.
//   - X0 wide GEMM, fused pipeline (L0||X1proj||L1), vocab epilogue:
//     all byte-identical to r18's proven best.
// ---------------------------------------------------------------------------

#define B_  16
#define T_  256
#define H_  256
#define V_  32000
#define G4  1024

#define LTPB 512   // 8 waves
#define FSTR 32    // flag stride in ints (one 128B line per flag)

typedef unsigned short u16;
typedef unsigned long long u64;
typedef __attribute__((ext_vector_type(8))) short  short8;
typedef __attribute__((ext_vector_type(4))) short  short4v;
typedef __attribute__((ext_vector_type(4))) float  f32x4;
typedef __attribute__((ext_vector_type(2))) float  f32x2;

static __device__ __forceinline__ float bf2f(u16 u) {
  uint32_t i = ((uint32_t)u) << 16;
  return __builtin_bit_cast(float, i);
}
static __device__ __forceinline__ u16 f2bf(float f) {
  uint32_t i = __builtin_bit_cast(uint32_t, f);
  uint32_t lsb = (i >> 16) & 1u;
  i += 0x7fffu + lsb;
  return (u16)(i >> 16);
}
static __device__ __forceinline__ float sigf(float x) {
  return 1.0f / (1.0f + __expf(-x));
}
static __device__ __forceinline__ float tanhfast(float x) {
  return 1.0f - 2.0f / (1.0f + __expf(2.0f * x));
}

// OCP e4m3fn encode (bias 7, max 448, RNE). Same encoder for W-pack and h.
static __device__ __forceinline__ uint32_t f32_to_e4m3(float f) {
  uint32_t u = __builtin_bit_cast(uint32_t, f);
  uint32_t s = (u >> 24) & 0x80u;
  uint32_t mag = u & 0x7fffffffu;
  if (mag >= 0x43E00000u) return s | 0x7Eu;
  if (mag < 0x3C800000u) {
    float af = __builtin_bit_cast(float, mag);
    int q = (int)rintf(af * 512.0f);
    if (q >= 8) return s | 0x08u;
    return s | (uint32_t)q;
  }
  uint32_t lsb = (mag >> 20) & 1u;
  mag += 0x7ffffu + lsb;
  int e = (int)(mag >> 23) - 120;
  uint32_t m3 = (mag >> 20) & 7u;
  if (e >= 16) return s | 0x7Eu;
  return s | ((uint32_t)e << 3) | m3;
}

// ------------------------------ prep kernel --------------------------------

static __device__ __forceinline__ void packWg_body(
    const float* __restrict__ Whh, u16* __restrict__ pk, int i) {
  int lane = i & 63;
  int fb = (i >> 6) & 15;
  int w  = i >> 10;
  int cb = fb >> 3, ks = fb & 7;
  int row = 512 + w * 32 + cb * 16 + (lane & 15);
  int kb  = ks * 32 + (lane >> 4) * 8;
  const float* src = Whh + (size_t)row * 256 + kb;
  short8 v;
  #pragma unroll
  for (int j = 0; j < 8; j++) v[j] = (short)f2bf(src[j]);
  *(short8*)(pk + (size_t)i * 8) = v;
}

static __device__ __forceinline__ void packW8_body(
    const float* __restrict__ Whh, u64* __restrict__ pk, int i) {
  int lane = i & 63;
  int fo = (i >> 6) % 48;
  int w  = (i >> 6) / 48;
  int g8 = fo >> 4, cb = (fo >> 3) & 1, ks = fo & 7;
  int base = (g8 == 0) ? 0 : (g8 == 1 ? 256 : 768);
  int row = base + w * 32 + cb * 16 + (lane & 15);
  int kb  = ks * 32 + (lane >> 4) * 8;
  const float* src = Whh + (size_t)row * 256 + kb;
  u64 p = 0;
  #pragma unroll
  for (int j = 0; j < 8; j++)
    p |= ((u64)f32_to_e4m3(src[j])) << (8 * j);
  pk[i] = p;
}

// All prep in one dispatch: W_hh packs / FiLM / bias sums / flags on the
// first 77824 threads; bf16 converts + gather grid-strided over all threads.
__global__ void k_prep(
    const float* __restrict__ Wih0, u16* __restrict__ Wih0b,
    const float* __restrict__ Wih1, u16* __restrict__ Wih1b,
    const float* __restrict__ Wout, u16* __restrict__ Woutb,
    const int* __restrict__ seq, const float* __restrict__ emb,
    u16* __restrict__ xb,
    const float* __restrict__ Whh0, u16* __restrict__ WpG0, u64* __restrict__ Wp80,
    const float* __restrict__ Whh1, u16* __restrict__ WpG1, u64* __restrict__ Wp81,
    const float* __restrict__ z,
    const float* __restrict__ Wg, const float* __restrict__ bg,
    const float* __restrict__ Wb, const float* __restrict__ bb,
    float* __restrict__ gamma, float* __restrict__ beta,
    const float* __restrict__ bih0, const float* __restrict__ bhh0,
    float* __restrict__ b01,
    const float* __restrict__ bih1, const float* __restrict__ bhh1,
    float* __restrict__ b11,
    int* __restrict__ flags) {
  const int i0 = blockIdx.x * blockDim.x + threadIdx.x;

  // ---- prepB portion: one item per thread ----
  if (i0 < 8192) {
    packWg_body(Whh0, WpG0, i0);
  } else if (i0 < 16384) {
    packWg_body(Whh1, WpG1, i0 - 8192);
  } else if (i0 < 40960) {
    packW8_body(Whh0, Wp80, i0 - 16384);
  } else if (i0 < 65536) {
    packW8_body(Whh1, Wp81, i0 - 40960);
  } else if (i0 < 73728) {
    int o = i0 - 65536;            // 8192: gamma|beta
    int which = o >> 12;
    int p = o & 4095;
    int b = p >> 8, h = p & 255;
    const float* W  = which ? Wb : Wg;
    const float* bi = which ? bb : bg;
    float acc = bi[h];
    const float* zr = z + b * 256;
    const float* wr = W + h * 256;
    #pragma unroll 8
    for (int k = 0; k < 256; k++) acc += zr[k] * wr[k];
    (which ? beta : gamma)[p] = acc;
  } else if (i0 < 74752) {
    int j = i0 - 73728;
    b01[j] = bih0[j] + bhh0[j];
  } else if (i0 < 75776) {
    int j = i0 - 74752;
    b11[j] = bih1[j] + bhh1[j];
  } else if (i0 < 77824) {
    flags[i0 - 75776] = 0;          // flagA+flagB, 1024 ints (+slack)
  }

  // ---- prepA portion: grid-stride converts + gather ----
  const int N1 = G4 * H_;                    // 262144
  const int N2 = N1 + G4 * H_;               // 524288
  const int N3 = N2 + V_ * H_;               // 8716288
  const int N4 = N3 + B_ * T_ * (H_ / 4);    // 8978432
  const int stride = gridDim.x * blockDim.x;
  for (int i = i0; i < N4; i += stride) {
    if (i < N1) {
      Wih0b[i] = f2bf(Wih0[i]);
    } else if (i < N2) {
      int j = i - N1;
      Wih1b[j] = f2bf(Wih1[j]);
    } else if (i < N3) {
      int j = i - N2;
      Woutb[j] = f2bf(Wout[j]);
    } else {
      int j = i - N3;
      int e4 = j & 63, bt = j >> 6;
      int t = bt & 255, b = bt >> 8;
      int row = seq[b * 257 + t];
      short4v p;
      if (row == 0) {
        p[0] = 0; p[1] = 0; p[2] = 0; p[3] = 0;
      } else {
        f32x4 v = *(const f32x4*)(emb + (size_t)row * 256 + e4 * 4);
        p[0] = (short)f2bf(v[0]); p[1] = (short)f2bf(v[1]);
        p[2] = (short)f2bf(v[2]); p[3] = (short)f2bf(v[3]);
      }
      *(short4v*)(xb + (size_t)bt * 256 + e4 * 4) = p;
    }
  }
}

// ------------------------------ bf16 GEMM (X0) -----------------------------
// C(M,N) fp32 = A(M,K)bf16 @ B(N,K)bf16^T + bias(N), permuted X layout:
// col = g*256 + r -> ocol = (r>>5)*128 + (r&15)*8 + g*2 + ((r>>4)&1).

__global__ __launch_bounds__(256) void k_gemm_bt(
    const u16* __restrict__ A, const u16* __restrict__ Bm,
    const float* __restrict__ bias, float* __restrict__ C,
    int M, int N, int K) {
  __shared__ u16 sA[128 * 40];
  __shared__ u16 sB[128 * 40];
  const int tid  = threadIdx.x;
  const int lane = tid & 63;
  const int wv   = tid >> 6;
  const int wr   = wv >> 1, wc = wv & 1;
  const int m0 = blockIdx.y * 128, n0 = blockIdx.x * 128;
  const int rr = tid >> 2;
  const int cc = (tid & 3) * 8;

  f32x4 acc[4][4];
  #pragma unroll
  for (int m = 0; m < 4; m++)
    #pragma unroll
    for (int n = 0; n < 4; n++) acc[m][n] = (f32x4){0.f, 0.f, 0.f, 0.f};

  for (int ks = 0; ks < K; ks += 32) {
    short8 va0 = *(const short8*)(A  + (size_t)(m0 + rr)      * K + ks + cc);
    short8 va1 = *(const short8*)(A  + (size_t)(m0 + rr + 64) * K + ks + cc);
    short8 vb0 = *(const short8*)(Bm + (size_t)(n0 + rr)      * K + ks + cc);
    short8 vb1 = *(const short8*)(Bm + (size_t)(n0 + rr + 64) * K + ks + cc);
    __syncthreads();
    *(short8*)&sA[(rr)      * 40 + cc] = va0;
    *(short8*)&sA[(rr + 64) * 40 + cc] = va1;
    *(short8*)&sB[(rr)      * 40 + cc] = vb0;
    *(short8*)&sB[(rr + 64) * 40 + cc] = vb1;
    __syncthreads();
    const int kc = (lane >> 4) * 8;
    short8 af[4], bfr[4];
    #pragma unroll
    for (int m = 0; m < 4; m++)
      af[m] = *(const short8*)&sA[(wr * 64 + m * 16 + (lane & 15)) * 40 + kc];
    #pragma unroll
    for (int n = 0; n < 4; n++)
      bfr[n] = *(const short8*)&sB[(wc * 64 + n * 16 + (lane & 15)) * 40 + kc];
    #pragma unroll
    for (int m = 0; m < 4; m++)
      #pragma unroll
      for (int n = 0; n < 4; n++)
        acc[m][n] = __builtin_amdgcn_mfma_f32_16x16x32_bf16(af[m], bfr[n], acc[m][n], 0, 0, 0);
  }

  #pragma unroll
  for (int m = 0; m < 4; m++) {
    int row = m0 + wr * 64 + m * 16 + ((lane >> 4) << 2);
    #pragma unroll
    for (int n = 0; n < 4; n++) {
      int col = n0 + wc * 64 + n * 16 + (lane & 15);
      float bv = bias[col];
      int g = col >> 8, r = col & 255;
      int ocol = (r >> 5) * 128 + (r & 15) * 8 + g * 2 + ((r >> 4) & 1);
      #pragma unroll
      for (int i = 0; i < 4; i++)
        C[(size_t)(row + i) * N + ocol] = acc[m][n][i] + bv;
    }
  }
}

// ----------------------------- fused roles ---------------------------------

static __device__ __forceinline__ void lstm_role(
    const float* __restrict__ Xpre, const u16* __restrict__ WpkG,
    const u64* __restrict__ Wpk8, u16* __restrict__ outb,
    const float* __restrict__ gamma, const float* __restrict__ beta,
    int mode, int s, int* flagOut, const int* flagIn,
    u16 (*hbuf)[256], u64 (*h8buf)[32]) {
  const int tid  = threadIdx.x;
  const int lane = tid & 63;
  const int w    = tid >> 6;
  const int l15  = lane & 15;
  const int lhi  = lane >> 4;

  short8 wgm[16];
  {
    const u16* bp = WpkG + ((size_t)(w * 16) * 64 + lane) * 8;
    #pragma unroll
    for (int f = 0; f < 16; ++f)
      wgm[f] = *(const short8*)(bp + (size_t)f * 512);
  }
  u64 w8r[48];
  {
    const u64* p8 = Wpk8 + (size_t)(w * 48) * 64 + lane;
    #pragma unroll
    for (int f = 0; f < 48; ++f)
      w8r[f] = p8[(size_t)f * 64];
  }

  const int col0 = w * 32 + l15;
  const int col1 = col0 + 16;
  float cs0 = 0.f, cs1 = 0.f;
  float gm0 = 1.f, gm1 = 1.f, bt0 = 0.f, bt1 = 0.f;
  if (mode) {
    gm0 = gamma[s * 256 + col0]; bt0 = beta[s * 256 + col0];
    gm1 = gamma[s * 256 + col1]; bt1 = beta[s * 256 + col1];
  }

  if (flagIn) {
    if (tid == 0) {
      while (__hip_atomic_load(flagIn, __ATOMIC_RELAXED,
                               __HIP_MEMORY_SCOPE_AGENT) < 1) { }
    }
    __syncthreads();
    __builtin_amdgcn_fence(__ATOMIC_ACQUIRE, "agent");
  }

  const float* xptr = Xpre + (size_t)s * T_ * 1024 + (size_t)(w * 16 + l15) * 8;

  // ---- t = 0 ----
  f32x4 xa = *(const f32x4*)(xptr);
  f32x4 xg = *(const f32x4*)(xptr + 4);
  {
    float cn0 = sigf(xa[2]) * cs0 + sigf(xa[0]) * tanhfast(xg[0]);
    float hn0 = sigf(xg[2]) * tanhfast(cn0);
    cs0 = cn0;
    float cn1 = sigf(xa[3]) * cs1 + sigf(xa[1]) * tanhfast(xg[1]);
    float hn1 = sigf(xg[3]) * tanhfast(cn1);
    cs1 = cn1;
    u16 h0 = f2bf(hn0), h1 = f2bf(hn1);
    if (lhi == 0) {
      hbuf[0][col0] = h0;
      hbuf[0][col1] = h1;
      ((uint8_t*)h8buf[0])[col0] = (uint8_t)f32_to_e4m3(hn0);
      ((uint8_t*)h8buf[0])[col1] = (uint8_t)f32_to_e4m3(hn1);
      outb[(size_t)(s * T_) * 256 + col0] = mode ? f2bf(gm0 * hn0 + bt0) : h0;
      outb[(size_t)(s * T_) * 256 + col1] = mode ? f2bf(gm1 * hn1 + bt1) : h1;
    }
  }
  asm volatile("s_waitcnt lgkmcnt(0)" ::: "memory");
  __builtin_amdgcn_sched_barrier(0);
  __builtin_amdgcn_s_barrier();
  __builtin_amdgcn_sched_barrier(0);

  xa = *(const f32x4*)(xptr + 1024);
  xg = *(const f32x4*)(xptr + 1024 + 4);

  for (int t = 1; t < T_; ++t) {
    if (flagIn && (t & 15) == 15 && (t + 1) < T_) {
      const int need = ((t + 1) >> 4) + 1;
      if (tid == 0) {
        while (__hip_atomic_load(flagIn, __ATOMIC_RELAXED,
                                 __HIP_MEMORY_SCOPE_AGENT) < need) { }
      }
      __syncthreads();
      __builtin_amdgcn_fence(__ATOMIC_ACQUIRE, "agent");
    }

    const float* xn = xptr + (size_t)((t + 1 < T_) ? t + 1 : t) * 1024;
    f32x4 na = *(const f32x4*)(xn);
    f32x4 ng = *(const f32x4*)(xn + 4);

    const u16* hrd  = hbuf[(t + 1) & 1];
    const u64* h8rd = h8buf[(t + 1) & 1];

    f32x4 aI[2], aF[2], aG[2], aO[2];
    #pragma unroll
    for (int i = 0; i < 2; ++i) {
      aI[i] = (f32x4){0.f, 0.f, 0.f, 0.f};
      aF[i] = (f32x4){0.f, 0.f, 0.f, 0.f};
      aG[i] = (f32x4){0.f, 0.f, 0.f, 0.f};
      aO[i] = (f32x4){0.f, 0.f, 0.f, 0.f};
    }
    #pragma unroll
    for (int ks = 0; ks < 8; ++ks) {
      short8 a  = *(const short8*)&hrd[ks * 32 + lhi * 8];
      u64    a8 = h8rd[ks * 4 + lhi];
      aG[0] = __builtin_amdgcn_mfma_f32_16x16x32_bf16(a, wgm[ks],     aG[0], 0, 0, 0);
      aG[1] = __builtin_amdgcn_mfma_f32_16x16x32_bf16(a, wgm[8 + ks], aG[1], 0, 0, 0);
      aI[0] = __builtin_amdgcn_mfma_f32_16x16x32_fp8_fp8((long)a8, (long)w8r[ks],      aI[0], 0, 0, 0);
      aI[1] = __builtin_amdgcn_mfma_f32_16x16x32_fp8_fp8((long)a8, (long)w8r[8 + ks],  aI[1], 0, 0, 0);
      aF[0] = __builtin_amdgcn_mfma_f32_16x16x32_fp8_fp8((long)a8, (long)w8r[16 + ks], aF[0], 0, 0, 0);
      aF[1] = __builtin_amdgcn_mfma_f32_16x16x32_fp8_fp8((long)a8, (long)w8r[24 + ks], aF[1], 0, 0, 0);
      aO[0] = __builtin_amdgcn_mfma_f32_16x16x32_fp8_fp8((long)a8, (long)w8r[32 + ks], aO[0], 0, 0, 0);
      aO[1] = __builtin_amdgcn_mfma_f32_16x16x32_fp8_fp8((long)a8, (long)w8r[40 + ks], aO[1], 0, 0, 0);
    }

    float iv0 = aI[0][0] + xa[0], iv1 = aI[1][0] + xa[1];
    float fv0 = aF[0][0] + xa[2], fv1 = aF[1][0] + xa[3];
    float gv0 = aG[0][0] + xg[0], gv1 = aG[1][0] + xg[1];
    float ov0 = aO[0][0] + xg[2], ov1 = aO[1][0] + xg[3];

    float cn0 = sigf(fv0) * cs0 + sigf(iv0) * tanhfast(gv0);
    float hn0 = sigf(ov0) * tanhfast(cn0);
    cs0 = cn0;
    float cn1 = sigf(fv1) * cs1 + sigf(iv1) * tanhfast(gv1);
    float hn1 = sigf(ov1) * tanhfast(cn1);
    cs1 = cn1;

    u16 h0 = f2bf(hn0), h1 = f2bf(hn1);
    if (lhi == 0) {
      hbuf[t & 1][col0] = h0;
      hbuf[t & 1][col1] = h1;
      ((uint8_t*)h8buf[t & 1])[col0] = (uint8_t)f32_to_e4m3(hn0);
      ((uint8_t*)h8buf[t & 1])[col1] = (uint8_t)f32_to_e4m3(hn1);
      outb[((size_t)(s * T_ + t)) * 256 + col0] = mode ? f2bf(gm0 * hn0 + bt0) : h0;
      outb[((size_t)(s * T_ + t)) * 256 + col1] = mode ? f2bf(gm1 * hn1 + bt1) : h1;
    }

    if (flagOut && (t & 15) == 15) {
      __syncthreads();
      if (tid == 0) {
        __builtin_amdgcn_fence(__ATOMIC_RELEASE, "agent");
        __hip_atomic_store(flagOut, t + 1, __ATOMIC_RELAXED,
                           __HIP_MEMORY_SCOPE_AGENT);
      }
    } else {
      asm volatile("s_waitcnt lgkmcnt(0)" ::: "memory");
      __builtin_amdgcn_sched_barrier(0);
      __builtin_amdgcn_s_barrier();
      __builtin_amdgcn_sched_barrier(0);
    }

    xa = na;
    xg = ng;
  }
}

// gate-projection worker: dst(s, t0..t0+15, :) = src rows @ W^T + bias (permuted)
static __device__ __forceinline__ void proj_role(
    const u16* __restrict__ src, const u16* __restrict__ Wb_,
    const float* __restrict__ bias, float* __restrict__ dst,
    int s, const int* flagIn, int* flagOut) {
  const int tid  = threadIdx.x;
  const int lane = tid & 63;
  const int w    = tid >> 6;
  const int l15  = lane & 15;
  const int lhi  = lane >> 4;

  for (int tc = 0; tc < 16; ++tc) {
    if (flagIn) {
      const int need = (tc + 1) * 16;
      if (tid == 0) {
        while (__hip_atomic_load(flagIn, __ATOMIC_RELAXED,
                                 __HIP_MEMORY_SCOPE_AGENT) < need) { }
      }
      __syncthreads();
      __builtin_amdgcn_fence(__ATOMIC_ACQUIRE, "agent");
    }

    const int t0 = tc * 16;
    short8 afr[8];
    #pragma unroll
    for (int ks = 0; ks < 8; ++ks)
      afr[ks] = *(const short8*)(src + ((size_t)(s * T_ + t0 + l15)) * 256 + ks * 32 + lhi * 8);

    #pragma unroll
    for (int nt = 0; nt < 8; ++nt) {
      const int colb = w * 128 + nt * 16 + l15;
      f32x4 acc = (f32x4){0.f, 0.f, 0.f, 0.f};
      const u16* bp = Wb_ + (size_t)colb * 256 + lhi * 8;
      #pragma unroll
      for (int ks = 0; ks < 8; ++ks) {
        short8 bf = *(const short8*)(bp + ks * 32);
        acc = __builtin_amdgcn_mfma_f32_16x16x32_bf16(afr[ks], bf, acc, 0, 0, 0);
      }
      const int g = colb >> 8, r = colb & 255;
      const int ocol = (r >> 5) * 128 + (r & 15) * 8 + g * 2 + ((r >> 4) & 1);
      const float bv = bias[colb];
      #pragma unroll
      for (int i = 0; i < 4; ++i) {
        int trow = t0 + lhi * 4 + i;
        dst[((size_t)(s * T_ + trow)) * 1024 + ocol] = acc[i] + bv;
      }
    }

    __syncthreads();
    if (tid == 0) {
      __builtin_amdgcn_fence(__ATOMIC_RELEASE, "agent");
      __hip_atomic_store(flagOut, tc + 1, __ATOMIC_RELAXED,
                         __HIP_MEMORY_SCOPE_AGENT);
    }
  }
}

__global__ __launch_bounds__(LTPB, 2) void k_fused(
    float* __restrict__ X0, float* __restrict__ X1,
    const u16* __restrict__ WpG0, const u64* __restrict__ Wp80,
    const u16* __restrict__ WpG1, const u64* __restrict__ Wp81,
    const u16* __restrict__ Wih1b, const float* __restrict__ b11,
    u16* __restrict__ h1b, u16* __restrict__ filmb,
    const float* __restrict__ gamma, const float* __restrict__ beta,
    int* __restrict__ flagA, int* __restrict__ flagB) {
  __shared__ __align__(16) char smem[1536];

  const int bid = blockIdx.x;
  if (bid < 16) {
    // L0: X0 fully materialized by the preceding dispatch -> fence-free.
    lstm_role(X0, WpG0, Wp80, h1b, gamma, beta, 0, bid,
              &flagA[bid * FSTR], nullptr,
              (u16(*)[256])smem, (u64(*)[32])(smem + 1024));
  } else if (bid < 32) {
    const int s = bid - 16;
    proj_role(h1b, Wih1b, b11, X1, s, &flagA[s * FSTR], &flagB[s * FSTR]);
  } else {
    const int s = bid - 32;
    lstm_role(X1, WpG1, Wp81, filmb, gamma, beta, 1, s,
              nullptr, &flagB[s * FSTR],
              (u16(*)[256])smem, (u64(*)[32])(smem + 1024));
  }
}

// ------------------------- trailing vocab GEMM -----------------------------
// 2000 blocks x 8 tiles each (exact). XCD-chunked mapping: blocks presumed
// on XCD x (bid&7) take the contiguous j-range [x*2000, x*2000+2000) so an
// XCD's CUs share Wo column groups in their L2. Tile: M=64, N=128,
// m-fastest within the range. LDS-staged A (stride 264) + full-line stores.
__global__ __launch_bounds__(LTPB, 2) void k_vocab(
    const u16* __restrict__ filmb, const u16* __restrict__ Wo,
    const float* __restrict__ bout, float* __restrict__ out) {
  __shared__ u16   sA[64 * 264];
  __shared__ float sC[64 * 132];
  const int tid  = threadIdx.x;
  const int lane = tid & 63;
  const int w    = tid >> 6;
  const int l15  = lane & 15;
  const int lhi  = lane >> 4;

  const int xcd = blockIdx.x & 7;
  const int idx = blockIdx.x >> 3;    // 0..249

  #pragma unroll 1
  for (int it = 0; it < 8; ++it) {
    const int j = xcd * 2000 + it * 250 + idx;
    const int mt = j & 63;
    const int nt = j >> 6;
    const int m0 = mt * 64;
    const int n0 = nt * 128;
    const int colb = n0 + w * 16 + l15;

    {
      const int r = tid >> 3, c = (tid & 7) * 32;
      const u16* srow = filmb + (size_t)(m0 + r) * 256 + c;
      #pragma unroll
      for (int k = 0; k < 4; ++k)
        *(short8*)&sA[r * 264 + c + k * 8] = *(const short8*)(srow + k * 8);
    }

    short8 bfr[8];
    #pragma unroll
    for (int ks = 0; ks < 8; ++ks)
      bfr[ks] = *(const short8*)(Wo + (size_t)colb * 256 + ks * 32 + lhi * 8);
    __syncthreads();

    f32x4 acc[4];
    #pragma unroll
    for (int mi = 0; mi < 4; ++mi) acc[mi] = (f32x4){0.f, 0.f, 0.f, 0.f};
    #pragma unroll
    for (int ks = 0; ks < 8; ++ks) {
      #pragma unroll
      for (int mi = 0; mi < 4; ++mi) {
        short8 a = *(const short8*)&sA[(mi * 16 + l15) * 264 + ks * 32 + lhi * 8];
        acc[mi] = __builtin_amdgcn_mfma_f32_16x16x32_bf16(a, bfr[ks], acc[mi], 0, 0, 0);
      }
    }

    const float bv = bout[colb];
    #pragma unroll
    for (int mi = 0; mi < 4; ++mi)
      #pragma unroll
      for (int i = 0; i < 4; ++i)
        sC[(mi * 16 + lhi * 4 + i) * 132 + w * 16 + l15] = acc[mi][i] + bv;
    __syncthreads();

    {
      const int rbase = w * 8;
      #pragma unroll
      for (int r = 0; r < 8; ++r) {
        const int row = rbase + r;
        f32x2 v;
        v[0] = sC[row * 132 + lane * 2];
        v[1] = sC[row * 132 + lane * 2 + 1];
        *(f32x2*)(out + (size_t)(m0 + row) * V_ + n0 + lane * 2) = v;
      }
    }
    __syncthreads();
  }
}

// ------------------------------ launcher -----------------------------------

extern "C" void kernel_launch(void* const* d_in, const int* in_sizes, int n_in,
                              void* d_out, int out_size, void* d_ws, size_t ws_size,
                              hipStream_t stream) {
  const float* z    = (const float*)d_in[0];
  const int*   seq  = (const int*)  d_in[1];
  const float* emb  = (const float*)d_in[2];
  const float* Wg   = (const float*)d_in[3];
  const float* bg   = (const float*)d_in[4];
  const float* Wb   = (const float*)d_in[5];
  const float* bb   = (const float*)d_in[6];
  const float* Wih0 = (const float*)d_in[7];
  const float* Whh0 = (const float*)d_in[8];
  const float* bih0 = (const float*)d_in[9];
  const float* bhh0 = (const float*)d_in[10];
  const float* Wih1 = (const float*)d_in[11];
  const float* Whh1 = (const float*)d_in[12];
  const float* bih1 = (const float*)d_in[13];
  const float* bhh1 = (const float*)d_in[14];
  const float* Wout = (const float*)d_in[15];
  const float* bout = (const float*)d_in[16];

  char* ws = (char*)d_ws;
  size_t off = 0;
  auto take = [&](size_t bytes) -> char* {
    char* p = ws + off;
    off = (off + bytes + 255) & ~(size_t)255;
    return p;
  };
  float* gamma  = (float*)take(B_ * H_ * 4);
  float* beta   = (float*)take(B_ * H_ * 4);
  float* b01    = (float*)take(G4 * 4);
  float* b11    = (float*)take(G4 * 4);
  u16*   Wih0b  = (u16*)  take((size_t)G4 * H_ * 2);
  u16*   Wih1b  = (u16*)  take((size_t)G4 * H_ * 2);
  u16*   WpG0   = (u16*)  take((size_t)8 * 16 * 64 * 8 * 2);
  u64*   Wp80   = (u64*)  take((size_t)8 * 48 * 64 * 8);
  u16*   WpG1   = (u16*)  take((size_t)8 * 16 * 64 * 8 * 2);
  u64*   Wp81   = (u64*)  take((size_t)8 * 48 * 64 * 8);
  u16*   Woutb  = (u16*)  take((size_t)V_ * H_ * 2);
  u16*   xb     = (u16*)  take((size_t)B_ * T_ * H_ * 2);
  float* X0     = (float*)take((size_t)B_ * T_ * G4 * 4);
  float* X1     = (float*)take((size_t)B_ * T_ * G4 * 4);
  u16*   h1b    = (u16*)  take((size_t)B_ * T_ * H_ * 2);
  u16*   filmb  = (u16*)  take((size_t)B_ * T_ * H_ * 2);
  int*   flagA  = (int*)  take(B_ * FSTR * 4);
  int*   flagB  = (int*)  take(B_ * FSTR * 4);
  (void)ws_size; (void)in_sizes; (void)n_in; (void)out_size;

  // prep: single merged dispatch
  k_prep<<<4096, 256, 0, stream>>>(
      Wih0, Wih0b, Wih1, Wih1b, Wout, Woutb, seq, emb, xb,
      Whh0, WpG0, Wp80, Whh1, WpG1, Wp81,
      z, Wg, bg, Wb, bb, gamma, beta,
      bih0, bhh0, b01, bih1, bhh1, b11, flagA);

  // X0 projection: wide dispatch; boundary = free acquire for L0
  k_gemm_bt<<<dim3(G4 / 128, (B_ * T_) / 128), 256, 0, stream>>>(
      xb, Wih0b, b01, X0, B_ * T_, G4, H_);

  // fused pipeline: L0 || X1proj || L1  (48 blocks)
  k_fused<<<48, LTPB, 0, stream>>>(
      X0, X1, WpG0, Wp80, WpG1, Wp81, Wih1b, b11,
      h1b, filmb, gamma, beta, flagA, flagB);

  // trailing vocab GEMM (2000 blocks x 8 tiles, XCD-chunked)
  k_vocab<<<2000, LTPB, 0, stream>>>(filmb, Woutb, bout, (float*)d_out);
}